// Round 8
// baseline (270.784 us; speedup 1.0000x reference)
//
#include <hip/hip_runtime.h>
#include <hip/hip_bf16.h>

typedef short bf16x8 __attribute__((ext_vector_type(8)));
typedef float f32x4 __attribute__((ext_vector_type(4)));
typedef _Float16 f16x2 __attribute__((ext_vector_type(2)));
typedef _Float16 f16x8 __attribute__((ext_vector_type(8)));

// ---------- helpers ----------
static __device__ __forceinline__ float bf2f(unsigned short u) {
  return __uint_as_float(((unsigned)u) << 16);
}
static __device__ __forceinline__ unsigned short f2bf(float f) {
  unsigned u = __float_as_uint(f);
  u += 0x7fffu + ((u >> 16) & 1u);   // RNE
  return (unsigned short)(u >> 16);
}
static __device__ __forceinline__ unsigned packbf(float a, float b) {
  return (unsigned)f2bf(a) | ((unsigned)f2bf(b) << 16);
}
// tanh-gelu via hardware exp: tanh(z) = 1 - 2/(exp(2z)+1)
static __device__ __forceinline__ float gelu_fast(float a) {
  float u = a * (1.5957691216057308f + 0.07135481627f * a * a);  // 2z
  float e = __expf(u);
  float r = __builtin_amdgcn_rcpf(e + 1.f);
  return a - a * r;   // a*(1 - 1/(e+1)) = 0.5a(1+tanh z)
}
static __device__ __forceinline__ float dot2(f16x2 a, f16x2 b, float c) {
#if __has_builtin(__builtin_amdgcn_fdot2)
  return __builtin_amdgcn_fdot2(a, b, c, false);
#else
  return c + (float)a[0] * (float)b[0] + (float)a[1] * (float)b[1];
#endif
}
template <typename T, typename F>
static __device__ __forceinline__ T bcast(F v) {
  union { F f; T t; } u; u.f = v; return u.t;
}
// f16 bits -> e5m2 byte (RNE truncation of top byte)
static __device__ __forceinline__ unsigned char f16_to_bf8(_Float16 h) {
  unsigned short b = bcast<unsigned short>(h);
  unsigned t = (unsigned)b + 0x7Fu + ((b >> 8) & 1u);
  return (unsigned char)(t >> 8);
}

// param-block element offsets (bf16 canonical)
#define PC_G1   0
#define PC_B1   128
#define PC_WQ   256
#define PC_BQ   16640
#define PC_WK   16768
#define PC_BK   33152
#define PC_WV   33280
#define PC_BV   49664
#define PC_EB   49792
#define PC_WO   49824
#define PC_BO   66208
#define PC_G2   66336
#define PC_B2   66464
#define PC_W1   66592
#define PC_B1F  99360
#define PC_W2   99616
#define PC_B2F  132384
#define PC_TOT  132512
#define B_CONV  518   // ceil(PC_TOT/256)

#define MAXBUCK 512
#define OFLCAP  8192

// ---------- dtype detect ----------
__global__ void k_detect(const unsigned* __restrict__ x, int* __restrict__ flag) {
  __shared__ int cnt;
  if (threadIdx.x == 0) cnt = 0;
  __syncthreads();
  int good = 0;
  for (int i = threadIdx.x; i < 1024; i += 256) {
    float v = fabsf(bf2f((unsigned short)(x[i] & 0xFFFFu)));
    good += (v >= 0.0009765625f && v <= 32.0f) ? 1 : 0;
  }
  atomicAdd(&cnt, good);
  __syncthreads();
  if (threadIdx.x == 0) flag[0] = (cnt < 512) ? 1 : 0;   // 1 => inputs are f32
}

// ---------- fused: param prep (+weight repack) || binned edge scatter ----------
struct PP { const void* p[17]; };

static __device__ __forceinline__ unsigned short rdw(const void* p, int isf, int idx) {
  return isf ? f2bf(((const float*)p)[idx]) : ((const unsigned short*)p)[idx];
}
static __device__ __forceinline__ void pack_one(
    const void* w, int isf, int rs, int K, int ntl_n,
    unsigned short* __restrict__ dst, int nt0, int idx)
{
  int k32 = K >> 5;
  if (idx >= ntl_n * k32 * 64) return;
  int lane = idx & 63;
  int ks = (idx >> 6) % k32;
  int ntl = idx / (64 * k32);
  int m = lane & 15, q = lane >> 4;
  int col = ntl * 16 + m;
  int kb = ks * 32 + q * 8;
  unsigned short tmp[8];
  #pragma unroll
  for (int j = 0; j < 8; ++j) tmp[j] = rdw(w, isf, (kb + j) * rs + col);
  *(uint4*)&dst[(size_t)(((nt0 + ntl) * k32 + ks) * 64 + lane) * 8] = *(const uint4*)tmp;
}

// Blocks [0, B_CONV+66): param conversion + weight repack (needs flag).
// Blocks [B_CONV+66, +bb): binned scatter of edges into fixed-capacity bucket
// regions of tmp (bucket b owns [b*CAP, (b+1)*CAP)); per-block LDS histogram +
// one global atomic per (block,bucket) reserves a contiguous run. Rare overflow
// (run past CAP) spills per-edge to ofl[] -- exactness for any input.
__global__ __launch_bounds__(256) void k_prep(
    PP pp, const int* __restrict__ flag, unsigned short* __restrict__ pc,
    unsigned short* __restrict__ wqkvp, unsigned short* __restrict__ wop,
    unsigned short* __restrict__ w1p, unsigned short* __restrict__ w2p,
    unsigned short* __restrict__ bqkvb,
    const int* __restrict__ ei, const int* __restrict__ et,
    int* __restrict__ bfill, unsigned* __restrict__ tmp,
    int2* __restrict__ ofl, int* __restrict__ ofl_cnt,
    int E, int nbuck, int shift, int CAP, int bb)
{
  __shared__ int cnt[MAXBUCK];
  const int b = blockIdx.x, tid = threadIdx.x;
  if (b < B_CONV + 66) {
    const int isf = flag[0];
    if (b < B_CONV) {
      const int offs[18] = {PC_G1,PC_B1,PC_WQ,PC_BQ,PC_WK,PC_BK,PC_WV,PC_BV,PC_EB,
                            PC_WO,PC_BO,PC_G2,PC_B2,PC_W1,PC_B1F,PC_W2,PC_B2F,PC_TOT};
      int i = b * 256 + tid;
      if (i >= PC_TOT) return;
      int s = 0;
      while (i >= offs[s + 1]) ++s;
      pc[i] = rdw(pp.p[s], isf, i - offs[s]);
    } else if (b < B_CONV + 8)  pack_one(pp.p[2],  isf, 128, 128, 8,  wqkvp, 0,  (b - B_CONV) * 256 + tid);
    else if (b < B_CONV + 16)   pack_one(pp.p[4],  isf, 128, 128, 8,  wqkvp, 8,  (b - B_CONV - 8) * 256 + tid);
    else if (b < B_CONV + 24)   pack_one(pp.p[6],  isf, 128, 128, 8,  wqkvp, 16, (b - B_CONV - 16) * 256 + tid);
    else if (b < B_CONV + 32)   pack_one(pp.p[9],  isf, 128, 128, 8,  wop,   0,  (b - B_CONV - 24) * 256 + tid);
    else if (b < B_CONV + 48)   pack_one(pp.p[13], isf, 256, 128, 16, w1p,   0,  (b - B_CONV - 32) * 256 + tid);
    else if (b < B_CONV + 64)   pack_one(pp.p[15], isf, 128, 256, 8,  w2p,   0,  (b - B_CONV - 48) * 256 + tid);
    else {
      int i = (b - B_CONV - 64) * 256 + tid;
      if (i < 384) {
        int s = i >> 7, c = i & 127;
        const void* src = (s == 0) ? pp.p[3] : ((s == 1) ? pp.p[5] : pp.p[7]);
        bqkvb[i] = rdw(src, isf, c);
      }
    }
    return;
  }

  // ---- binned scatter ----
  const int bsb = b - (B_CONV + 66);
  const unsigned lowmask = (1u << shift) - 1u;
  for (int base = bsb * 4096; base < E; base += bb * 4096) {
    for (int i = tid; i < nbuck; i += 256) cnt[i] = 0;
    __syncthreads();
    unsigned pk[16]; int bk[16];
    #pragma unroll
    for (int u = 0; u < 16; ++u) {
      int e = base + u * 256 + tid;
      if (e < E) {
        unsigned s = (unsigned)ei[e];
        unsigned d = (unsigned)ei[E + e];
        unsigned t = (unsigned)et[e];
        int bq = min((int)(d >> shift), nbuck - 1);
        pk[u] = s | (t << 18) | ((d & lowmask) << 20);
        bk[u] = bq;
        atomicAdd(&cnt[bq], 1);
      } else bk[u] = -1;
    }
    __syncthreads();
    for (int i = tid; i < nbuck; i += 256) {
      int c = cnt[i];
      cnt[i] = c ? i * CAP + atomicAdd(&bfill[i], c) : 0;
    }
    __syncthreads();
    #pragma unroll
    for (int u = 0; u < 16; ++u) {
      if (bk[u] >= 0) {
        int pos = atomicAdd(&cnt[bk[u]], 1);
        if (pos < (bk[u] + 1) * CAP) {
          tmp[pos] = pk[u];
        } else {
          int oi = atomicAdd(ofl_cnt, 1);
          if (oi < OFLCAP) { int2 o; o.x = (int)pk[u]; o.y = bk[u]; ofl[oi] = o; }
        }
      }
    }
    __syncthreads();
  }
}

// ---------- fused: LN1+QKV GEMM || per-bucket CSR sort ----------
// Blocks [0, NB): LN1 + QKV via MFMA -> qb (f16) + kvb (e5m2, row = [k 8h x 16B][v ...]).
// Blocks [NB, NB+nbuck): sort bucket region of tmp into CSR order (packed) and
// emit rowptr; bucket base in packed = running sum of bfill (on-the-fly reduce).
__global__ __launch_bounds__(256) void k_lnqkv(
    const void* __restrict__ xin, const int* __restrict__ flag,
    const unsigned short* __restrict__ pc,
    const unsigned short* __restrict__ bias,
    const unsigned short* __restrict__ wpack,
    _Float16* __restrict__ qb, unsigned char* __restrict__ kvb, int N, int NB,
    const unsigned* __restrict__ tmp, const int* __restrict__ bfill,
    const int2* __restrict__ ofl, const int* __restrict__ ofl_cnt,
    int* __restrict__ rowptr, unsigned* __restrict__ packed,
    int nbuck, int shift, int CAP)
{
  __shared__ __align__(16) char shraw[64 * 136 * 2];   // 17408 B arena
  const int tid = threadIdx.x, lane = tid & 63, wv = tid >> 6;

  if ((int)blockIdx.x >= NB) {
    // ---- bucketsort ----
    int* cnt = (int*)shraw;                  // 1024 ints
    int* cur = (int*)(shraw + 4096);         // 1024 ints
    int* ws  = (int*)(shraw + 8192);         // 4 ints
    int* rs  = (int*)(shraw + 8224);         // 8 ints
    int* carry_s = (int*)(shraw + 8256);
    const int bw = 1 << shift;
    const int b2 = (int)blockIdx.x - NB;
    const int n0 = b2 << shift;

    int s_before = 0, s_all = 0;
    for (int i = tid; i < nbuck; i += 256) {
      int v = bfill[i];
      s_all += v;
      if (i < b2) s_before += v;
    }
    #pragma unroll
    for (int o = 1; o < 64; o <<= 1) {
      s_before += __shfl_xor(s_before, o);
      s_all    += __shfl_xor(s_all, o);
    }
    if (lane == 0) { rs[wv] = s_before; rs[4 + wv] = s_all; }
    for (int i = tid; i < bw; i += 256) cnt[i] = 0;
    if (tid == 0) *carry_s = 0;
    __syncthreads();
    const int beg = rs[0] + rs[1] + rs[2] + rs[3];
    const int tot = rs[4] + rs[5] + rs[6] + rs[7];
    const int stored = min(bfill[b2], CAP);
    const int tbase = b2 * CAP;
    if (b2 == 0 && tid == 0) rowptr[N] = tot;
    const int onum = min(*ofl_cnt, OFLCAP);

    for (int i = tid; i < stored; i += 256)
      atomicAdd(&cnt[(tmp[tbase + i] >> 20) & (unsigned)(bw - 1)], 1);
    for (int i = tid; i < onum; i += 256) {
      int2 o = ofl[i];
      if (o.y == b2) atomicAdd(&cnt[(((unsigned)o.x) >> 20) & (unsigned)(bw - 1)], 1);
    }
    __syncthreads();
    for (int base = 0; base < bw; base += 256) {
      int i = base + tid;
      int v = (i < bw) ? cnt[i] : 0;
      int s = v;
      #pragma unroll
      for (int o = 1; o < 64; o <<= 1) { int t = __shfl_up(s, o); if (lane >= o) s += t; }
      if (lane == 63) ws[wv] = s;
      int c = *carry_s;
      __syncthreads();
      int off = c;
      for (int k = 0; k < wv; ++k) off += ws[k];
      if (i < bw) {
        int excl = beg + off + s - v;
        cur[i] = excl;
        if (n0 + i < N) rowptr[n0 + i] = excl;
      }
      __syncthreads();
      if (tid == 0) *carry_s = c + ws[0] + ws[1] + ws[2] + ws[3];
      __syncthreads();
    }
    for (int i = tid; i < stored; i += 256) {
      unsigned pk = tmp[tbase + i];
      int dl = (int)((pk >> 20) & (unsigned)(bw - 1));
      int pos = atomicAdd(&cur[dl], 1);
      packed[pos] = pk;   // dlow bits stay in 20+; attn masks type with &3
    }
    for (int i = tid; i < onum; i += 256) {
      int2 o = ofl[i];
      if (o.y == b2) {
        unsigned pk = (unsigned)o.x;
        int dl = (int)((pk >> 20) & (unsigned)(bw - 1));
        int pos = atomicAdd(&cur[dl], 1);
        packed[pos] = pk;
      }
    }
    return;
  }

  // ---- LN1 + QKV ----
  unsigned short* H = (unsigned short*)shraw;   // 64 x 136
  const int row0 = blockIdx.x * 64;
  const int isf = flag[0];
  {
    const int rl = tid >> 2, c0 = (tid & 3) * 32;
    const int r = row0 + rl;
    float xv[32];
    if (r < N) {
      if (isf) {
        const float4* xp = (const float4*)((const float*)xin + (size_t)r * 128 + c0);
        #pragma unroll
        for (int u = 0; u < 8; ++u) {
          float4 f = xp[u];
          xv[u*4] = f.x; xv[u*4+1] = f.y; xv[u*4+2] = f.z; xv[u*4+3] = f.w;
        }
      } else {
        const uint4* xp = (const uint4*)((const unsigned short*)xin + (size_t)r * 128 + c0);
        #pragma unroll
        for (int u = 0; u < 4; ++u) {
          uint4 w = xp[u];
          unsigned ww[4] = {w.x, w.y, w.z, w.w};
          #pragma unroll
          for (int p = 0; p < 4; ++p) {
            xv[u*8 + 2*p]     = bf2f((unsigned short)ww[p]);
            xv[u*8 + 2*p + 1] = bf2f((unsigned short)(ww[p] >> 16));
          }
        }
      }
    } else {
      #pragma unroll
      for (int u = 0; u < 32; ++u) xv[u] = 0.f;
    }
    float s = 0.f, s2 = 0.f;
    #pragma unroll
    for (int u = 0; u < 32; ++u) { s += xv[u]; s2 += xv[u] * xv[u]; }
    s += __shfl_xor(s, 1); s2 += __shfl_xor(s2, 1);
    s += __shfl_xor(s, 2); s2 += __shfl_xor(s2, 2);
    float mean = s * (1.f / 128.f);
    float var  = fmaxf(s2 * (1.f / 128.f) - mean * mean, 0.f);
    float inv  = rsqrtf(var + 1e-5f);
    unsigned short hb[32];
    #pragma unroll
    for (int u = 0; u < 32; ++u) {
      int c = c0 + u;
      hb[u] = f2bf((xv[u] - mean) * inv * bf2f(pc[PC_G1 + c]) + bf2f(pc[PC_B1 + c]));
    }
    uint4* hp = (uint4*)&H[rl * 136 + c0];
    #pragma unroll
    for (int u = 0; u < 4; ++u) hp[u] = ((const uint4*)hb)[u];
  }
  __syncthreads();

  const int wave = wv;
  const int m = lane & 15, q = lane >> 4;
  bf16x8 a[16];
  #pragma unroll
  for (int rt = 0; rt < 4; ++rt) {
    const unsigned short* hrow = &H[(rt * 16 + m) * 136 + q * 8];
    #pragma unroll
    for (int ks = 0; ks < 4; ++ks) a[rt*4+ks] = *(const bf16x8*)&hrow[ks * 32];
  }
  const f32x4 z = {0.f, 0.f, 0.f, 0.f};
  #pragma unroll
  for (int p = 0; p < 3; ++p) {
    bf16x8 bfr[8];
    #pragma unroll
    for (int tt = 0; tt < 2; ++tt)
      #pragma unroll
      for (int ks = 0; ks < 4; ++ks)
        bfr[tt*4+ks] = *(const bf16x8*)&wpack[(size_t)(((wave*6 + 2*p + tt)*4 + ks)*64 + lane)*8];
    f32x4 c[4][2];
    #pragma unroll
    for (int rt = 0; rt < 4; ++rt) { c[rt][0] = z; c[rt][1] = z; }
    #pragma unroll
    for (int rt = 0; rt < 4; ++rt)
      #pragma unroll
      for (int ks = 0; ks < 4; ++ks) {
        c[rt][0] = __builtin_amdgcn_mfma_f32_16x16x32_bf16(a[rt*4+ks], bfr[ks],   c[rt][0], 0, 0, 0);
        c[rt][1] = __builtin_amdgcn_mfma_f32_16x16x32_bf16(a[rt*4+ks], bfr[4+ks], c[rt][1], 0, 0, 0);
      }
    #pragma unroll
    for (int tt = 0; tt < 2; ++tt) {
      int jj = (wave*6 + 2*p + tt) * 16 + m;
      float bv = bf2f(bias[jj]);
      #pragma unroll
      for (int rt = 0; rt < 4; ++rt)
        #pragma unroll
        for (int rr = 0; rr < 4; ++rr) {
          int row = row0 + rt*16 + q*4 + rr;
          if (row < N) {
            _Float16 hv = (_Float16)(c[rt][tt][rr] + bv);
            if (jj < 128) {
              qb[(size_t)row * 128 + jj] = hv;
            } else if (jj < 256) {
              int cc = jj - 128, h = cc >> 4, d = cc & 15;
              kvb[(size_t)row * 256 + h * 16 + d] = f16_to_bf8(hv);
            } else {
              int cc = jj - 256, h = cc >> 4, d = cc & 15;
              kvb[(size_t)row * 256 + 128 + h * 16 + d] = f16_to_bf8(hv);
            }
          }
        }
    }
  }
}

// ---------- fused attention + tail: block = 64 nodes ----------
// Phase 1 (attn): each wave computes 16 nodes' edge attention (lane=(edge,head),
// e5m2 KV, perm decode) and writes messages to LDS (hts as msg[64][136] bf16).
// Phase 2 (tail): msg@wo+residual -> LN2 -> FFN1(gelu) -> FFN2+residual -> out.
// No global msgb round-trip; tail compute of some blocks overlaps attn memory
// stalls of others (no inter-kernel barrier).
__global__ __launch_bounds__(256) void k_attail(
    const void* __restrict__ xin, const int* __restrict__ flag,
    const _Float16* __restrict__ qb, const unsigned char* __restrict__ kvb,
    const unsigned* __restrict__ packed, const int* __restrict__ rowptr,
    const unsigned short* __restrict__ wop, const unsigned short* __restrict__ w1p,
    const unsigned short* __restrict__ w2p, const unsigned short* __restrict__ pc,
    void* __restrict__ out, int N, int th)
{
  __shared__ unsigned short x1s[64 * 136];
  __shared__ unsigned short hts[64 * 264];  // attn: msg[64][136]; LN2: stride 136; FFN1-out: stride 264
  __shared__ float ebs[64];
  const int tid = threadIdx.x;
  const int row0 = blockIdx.x * 64;
  const int isf = flag[0];
  const int wave = tid >> 6, lane = tid & 63;
  const int m = lane & 15, q = lane >> 4;
  const f32x4 z = {0.f, 0.f, 0.f, 0.f};

  if (tid < th) ebs[tid] = bf2f(pc[PC_EB + tid]);

  // residual staging: x -> x1s
  {
    int rl = tid >> 2, c0 = (tid & 3) * 32;
    int r = row0 + rl;
    unsigned short hb[32];
    if (r < N) {
      if (isf) {
        const float4* xp = (const float4*)((const float*)xin + (size_t)r * 128 + c0);
        #pragma unroll
        for (int u = 0; u < 8; ++u) {
          float4 f = xp[u];
          hb[u*4] = f2bf(f.x); hb[u*4+1] = f2bf(f.y);
          hb[u*4+2] = f2bf(f.z); hb[u*4+3] = f2bf(f.w);
        }
      } else {
        const uint4* xp = (const uint4*)((const unsigned short*)xin + (size_t)r * 128 + c0);
        #pragma unroll
        for (int u = 0; u < 4; ++u) ((uint4*)hb)[u] = xp[u];
      }
    } else {
      #pragma unroll
      for (int u = 0; u < 32; ++u) hb[u] = 0;
    }
    #pragma unroll
    for (int u = 0; u < 4; ++u) ((uint4*)&x1s[rl * 136 + c0])[u] = ((const uint4*)hb)[u];
  }
  __syncthreads();   // ebs ready for attn phase

  // ---- phase 1: attention, 16 nodes per wave ----
  {
    const int h = lane & 7, el = lane >> 3;
    for (int i = 0; i < 16; ++i) {
      const int n = row0 + wave * 16 + i;
      unsigned short* mrow = &hts[(wave * 16 + i) * 136];
      if (n >= N) {
        if (el == 0) {
          uint4 zz = {0, 0, 0, 0};
          uint4* dst = (uint4*)&mrow[h * 16];
          dst[0] = zz; dst[1] = zz;
        }
        continue;
      }
      f16x8 qa, qc;
      {
        const _Float16* qp = qb + (size_t)n * 128 + h * 16;
        qa = *(const f16x8*)qp;
        qc = *(const f16x8*)(qp + 8);
      }
      const int beg = rowptr[n], end = rowptr[n + 1];
      float l = 0.f;
      f16x8 accA = {0, 0, 0, 0, 0, 0, 0, 0};
      f16x8 accB = {0, 0, 0, 0, 0, 0, 0, 0};

      if (beg < end) {
        const int last = end - 1;
        unsigned pk = packed[min(beg + el, last)];
        const unsigned char* kp = kvb + (size_t)(pk & 0x3FFFF) * 256 + h * 16;
        uint4 kw = *(const uint4*)kp;
        uint4 vw = *(const uint4*)(kp + 128);

        for (int base = beg; base < end; base += 8) {
          unsigned pk2 = 0; uint4 kw2, vw2;
          const bool more = (base + 8) < end;   // wave-uniform
          if (more) {
            pk2 = packed[min(base + 8 + el, last)];
            const unsigned char* kp2 = kvb + (size_t)(pk2 & 0x3FFFF) * 256 + h * 16;
            kw2 = *(const uint4*)kp2;
            vw2 = *(const uint4*)(kp2 + 128);
          }

          // decode k (16 e5m2 bytes -> 8 f16x2 via v_perm) and dot with q
          float s = 0.f;
          {
            unsigned kd[4] = {kw.x, kw.y, kw.z, kw.w};
            #pragma unroll
            for (int j = 0; j < 2; ++j) {
              f16x2 klo = bcast<f16x2>(__builtin_amdgcn_perm(0u, kd[j], 0x010c000cu));
              f16x2 khi = bcast<f16x2>(__builtin_amdgcn_perm(0u, kd[j], 0x030c020cu));
              f16x2 a0 = {qa[4*j], qa[4*j+1]}, a1 = {qa[4*j+2], qa[4*j+3]};
              s = dot2(a0, klo, s);
              s = dot2(a1, khi, s);
            }
            #pragma unroll
            for (int j = 0; j < 2; ++j) {
              f16x2 klo = bcast<f16x2>(__builtin_amdgcn_perm(0u, kd[2+j], 0x010c000cu));
              f16x2 khi = bcast<f16x2>(__builtin_amdgcn_perm(0u, kd[2+j], 0x030c020cu));
              f16x2 a0 = {qc[4*j], qc[4*j+1]}, a1 = {qc[4*j+2], qc[4*j+3]};
              s = dot2(a0, klo, s);
              s = dot2(a1, khi, s);
            }
          }
          float sc = fminf(s * 0.25f + ebs[((pk >> 18) & 3u) * 8 + h], 80.f);
          float pe = (base + el < end) ? __expf(sc) : 0.f;
          l += pe;
          _Float16 pf = (_Float16)pe;
          f16x8 p8 = {pf, pf, pf, pf, pf, pf, pf, pf};
          {
            unsigned vd[4] = {vw.x, vw.y, vw.z, vw.w};
            union { unsigned u[4]; f16x8 v; } va, vb;
            va.u[0] = __builtin_amdgcn_perm(0u, vd[0], 0x010c000cu);
            va.u[1] = __builtin_amdgcn_perm(0u, vd[0], 0x030c020cu);
            va.u[2] = __builtin_amdgcn_perm(0u, vd[1], 0x010c000cu);
            va.u[3] = __builtin_amdgcn_perm(0u, vd[1], 0x030c020cu);
            vb.u[0] = __builtin_amdgcn_perm(0u, vd[2], 0x010c000cu);
            vb.u[1] = __builtin_amdgcn_perm(0u, vd[2], 0x030c020cu);
            vb.u[2] = __builtin_amdgcn_perm(0u, vd[3], 0x010c000cu);
            vb.u[3] = __builtin_amdgcn_perm(0u, vd[3], 0x030c020cu);
            accA += p8 * va.v;
            accB += p8 * vb.v;
          }

          if (more) { pk = pk2; kw = kw2; vw = vw2; }
        }
      }

      #pragma unroll
      for (int mask = 8; mask <= 32; mask <<= 1) {
        l += __shfl_xor(l, mask);
        int2 ai = bcast<int2>(accA), bi = bcast<int2>(accB);
        int2 as, bs;
        as.x = __shfl_xor(ai.x, mask); as.y = __shfl_xor(ai.y, mask);
        bs.x = __shfl_xor(bi.x, mask); bs.y = __shfl_xor(bi.y, mask);
        accA += bcast<f16x8>(as);
        accB += bcast<f16x8>(bs);
      }
      if (el == 0) {
        float inv = 1.f / (l + 1e-9f);
        unsigned o[8];
        #pragma unroll
        for (int j = 0; j < 4; ++j)
          o[j] = packbf((float)accA[2*j] * inv, (float)accA[2*j+1] * inv);
        #pragma unroll
        for (int j = 0; j < 4; ++j)
          o[4+j] = packbf((float)accB[2*j] * inv, (float)accB[2*j+1] * inv);
        uint4* dst = (uint4*)&mrow[h * 16];
        uint4 d0 = {o[0], o[1], o[2], o[3]}, d1 = {o[4], o[5], o[6], o[7]};
        dst[0] = d0; dst[1] = d1;
      }
    }
  }
  __syncthreads();   // msg (hts) complete

  // ---- phase 2: tail ----
  bf16x8 b1[8];
  #pragma unroll
  for (int tt = 0; tt < 2; ++tt)
    #pragma unroll
    for (int ks = 0; ks < 4; ++ks)
      b1[tt*4+ks] = *(const bf16x8*)&wop[(size_t)(((2*wave + tt)*4 + ks)*64 + lane)*8];
  bf16x8 a1[16];
  #pragma unroll
  for (int rt = 0; rt < 4; ++rt) {
    const unsigned short* ap = &hts[(rt*16 + m) * 136 + q * 8];
    #pragma unroll
    for (int ks = 0; ks < 4; ++ks) a1[rt*4+ks] = *(const bf16x8*)&ap[ks * 32];
  }

  // GEMM1: attn_out @ wo (+bias +residual) -> x1s
  {
    f32x4 c[4][2];
    #pragma unroll
    for (int rt = 0; rt < 4; ++rt) { c[rt][0] = z; c[rt][1] = z; }
    #pragma unroll
    for (int rt = 0; rt < 4; ++rt)
      #pragma unroll
      for (int ks = 0; ks < 4; ++ks) {
        c[rt][0] = __builtin_amdgcn_mfma_f32_16x16x32_bf16(a1[rt*4+ks], b1[ks],   c[rt][0], 0, 0, 0);
        c[rt][1] = __builtin_amdgcn_mfma_f32_16x16x32_bf16(a1[rt*4+ks], b1[4+ks], c[rt][1], 0, 0, 0);
      }
    #pragma unroll
    for (int tt = 0; tt < 2; ++tt) {
      int col = (2*wave + tt) * 16 + m;
      float bv = bf2f(pc[PC_BO + col]);
      #pragma unroll
      for (int rt = 0; rt < 4; ++rt)
        #pragma unroll
        for (int rr = 0; rr < 4; ++rr) {
          int rl = rt*16 + q*4 + rr;
          float o = c[rt][tt][rr] + bv + bf2f(x1s[rl * 136 + col]);
          x1s[rl * 136 + col] = f2bf(o);
        }
    }
  }
  __syncthreads();   // all a1 reads done; hts reusable

  bf16x8 b2[16];
  #pragma unroll
  for (int u = 0; u < 4; ++u)
    #pragma unroll
    for (int ks = 0; ks < 4; ++ks)
      b2[u*4+ks] = *(const bf16x8*)&w1p[(size_t)(((4*wave + u)*4 + ks)*64 + lane)*8];

  // LN2
  {
    int rl = tid >> 2, c0 = (tid & 3) * 32;
    unsigned short hb[32];
    #pragma unroll
    for (int u = 0; u < 4; ++u) ((uint4*)hb)[u] = *(const uint4*)&x1s[rl * 136 + c0 + u * 8];
    float xv[32];
    #pragma unroll
    for (int u = 0; u < 32; ++u) xv[u] = bf2f(hb[u]);
    float s = 0.f, s2 = 0.f;
    #pragma unroll
    for (int u = 0; u < 32; ++u) { s += xv[u]; s2 += xv[u] * xv[u]; }
    s += __shfl_xor(s, 1); s2 += __shfl_xor(s2, 1);
    s += __shfl_xor(s, 2); s2 += __shfl_xor(s2, 2);
    float mean = s * (1.f / 128.f);
    float var  = fmaxf(s2 * (1.f / 128.f) - mean * mean, 0.f);
    float inv  = rsqrtf(var + 1e-5f);
    #pragma unroll
    for (int u = 0; u < 32; ++u) {
      int c = c0 + u;
      hb[u] = f2bf((xv[u] - mean) * inv * bf2f(pc[PC_G2 + c]) + bf2f(pc[PC_B2 + c]));
    }
    #pragma unroll
    for (int u = 0; u < 4; ++u) ((uint4*)&hts[rl * 136 + c0])[u] = ((const uint4*)hb)[u];
  }
  __syncthreads();

  bf16x8 a2[16];
  #pragma unroll
  for (int rt = 0; rt < 4; ++rt) {
    const unsigned short* hp = &hts[(rt*16 + m) * 136 + q * 8];
    #pragma unroll
    for (int ks = 0; ks < 4; ++ks) a2[rt*4+ks] = *(const bf16x8*)&hp[ks * 32];
  }
  __syncthreads();   // hts about to be reused (stride 264) as FFN1 output

  #pragma unroll
  for (int p = 0; p < 2; ++p) {
    f32x4 c[4][2];
    #pragma unroll
    for (int rt = 0; rt < 4; ++rt) { c[rt][0] = z; c[rt][1] = z; }
    #pragma unroll
    for (int rt = 0; rt < 4; ++rt)
      #pragma unroll
      for (int ks = 0; ks < 4; ++ks) {
        c[rt][0] = __builtin_amdgcn_mfma_f32_16x16x32_bf16(a2[rt*4+ks], b2[(2*p)*4+ks],   c[rt][0], 0, 0, 0);
        c[rt][1] = __builtin_amdgcn_mfma_f32_16x16x32_bf16(a2[rt*4+ks], b2[(2*p+1)*4+ks], c[rt][1], 0, 0, 0);
      }
    #pragma unroll
    for (int tt = 0; tt < 2; ++tt) {
      int col = (4*wave + 2*p + tt) * 16 + m;
      float bv = bf2f(pc[PC_B1F + col]);
      #pragma unroll
      for (int rt = 0; rt < 4; ++rt)
        #pragma unroll
        for (int rr = 0; rr < 4; ++rr)
          hts[(rt*16 + q*4 + rr) * 264 + col] = f2bf(gelu_fast(c[rt][tt][rr] + bv));
    }
  }

  bf16x8 b3[16];
  #pragma unroll
  for (int tt = 0; tt < 2; ++tt)
    #pragma unroll
    for (int ks = 0; ks < 8; ++ks)
      b3[tt*8+ks] = *(const bf16x8*)&w2p[(size_t)(((2*wave + tt)*8 + ks)*64 + lane)*8];
  __syncthreads();

  #pragma unroll
  for (int rt = 0; rt < 4; ++rt) {
    bf16x8 a3[8];
    const unsigned short* tp = &hts[(rt*16 + m) * 264 + q * 8];
    #pragma unroll
    for (int ks = 0; ks < 8; ++ks) a3[ks] = *(const bf16x8*)&tp[ks * 32];
    f32x4 c0 = z, c1 = z;
    #pragma unroll
    for (int ks = 0; ks < 8; ++ks) {
      c0 = __builtin_amdgcn_mfma_f32_16x16x32_bf16(a3[ks], b3[ks],   c0, 0, 0, 0);
      c1 = __builtin_amdgcn_mfma_f32_16x16x32_bf16(a3[ks], b3[8+ks], c1, 0, 0, 0);
    }
    #pragma unroll
    for (int tt = 0; tt < 2; ++tt) {
      f32x4 cc = tt ? c1 : c0;
      int col = (2*wave + tt) * 16 + m;
      float bv = bf2f(pc[PC_B2F + col]);
      #pragma unroll
      for (int rr = 0; rr < 4; ++rr) {
        int rl = rt*16 + q*4 + rr;
        int row = row0 + rl;
        if (row < N) {
          float o = cc[rr] + bv + bf2f(x1s[rl * 136 + col]);
          if (isf) ((float*)out)[(size_t)row * 128 + col] = o;
          else     ((unsigned short*)out)[(size_t)row * 128 + col] = f2bf(o);
        }
      }
    }
  }
}

// ---------- launch ----------
extern "C" void kernel_launch(void* const* d_in, const int* in_sizes, int n_in,
                              void* d_out, int out_size, void* d_ws, size_t ws_size,
                              hipStream_t stream)
{
  const void* x = d_in[0];
  const int* ei = (const int*)d_in[1];
  const int* et = (const int*)d_in[2];
  const int N = in_sizes[0] / 128;
  const int E = in_sizes[2];
  int th = in_sizes[13];
  if (th > 64) th = 64;

  int shift = 7;
  while ((((N + (1 << shift) - 1) >> shift) > MAXBUCK) && shift < 10) ++shift;
  const int nbuck = (N + (1 << shift) - 1) >> shift;
  const int CAP = ((2 * (E / nbuck) + 512) + 63) & ~63;   // >>10 sigma headroom

  char* ws = (char*)d_ws;
  size_t off = 0;
  auto alloc = [&](size_t bytes) -> void* {
    void* p = ws + off; off += (bytes + 255) & ~(size_t)255; return p;
  };
  int* flag = (int*)alloc(4);
  unsigned short* pc = (unsigned short*)alloc((size_t)PC_TOT * 2);
  _Float16* qb  = (_Float16*)alloc((size_t)N * 128 * 2);
  unsigned char* kvb = (unsigned char*)alloc((size_t)N * 256);
  unsigned* packed = (unsigned*)alloc((size_t)E * 4);
  unsigned* tmp = (unsigned*)alloc((size_t)nbuck * CAP * 4);
  int2* ofl = (int2*)alloc((size_t)OFLCAP * 8);
  int* rowptr = (int*)alloc((size_t)(N + 1) * 4);
  unsigned short* wqkvp = (unsigned short*)alloc((size_t)128 * 384 * 2);
  unsigned short* wop   = (unsigned short*)alloc((size_t)128 * 128 * 2);
  unsigned short* w1p   = (unsigned short*)alloc((size_t)128 * 256 * 2);
  unsigned short* w2p   = (unsigned short*)alloc((size_t)256 * 128 * 2);
  unsigned short* bqkvb = (unsigned short*)alloc(384 * 2);
  size_t zoff = off;
  int* bfill   = (int*)alloc((size_t)MAXBUCK * 4);
  int* ofl_cnt = (int*)alloc(4);
  hipMemsetAsync(ws + zoff, 0, off - zoff, stream);

  k_detect<<<1, 256, 0, stream>>>((const unsigned*)x, flag);

  PP pp;
  for (int i = 0; i < 17; ++i) pp.p[i] = d_in[5 + i];

  const int NB = (N + 63) / 64;
  const int bb = (E + 4095) / 4096;

  // fused: param prep || binned edge scatter
  k_prep<<<B_CONV + 66 + bb, 256, 0, stream>>>(
      pp, flag, pc, wqkvp, wop, w1p, w2p, bqkvb,
      ei, et, bfill, tmp, ofl, ofl_cnt, E, nbuck, shift, CAP, bb);

  // fused: LN1+QKV || per-bucket CSR sort
  k_lnqkv<<<NB + nbuck, 256, 0, stream>>>(
      x, flag, pc, bqkvb, wqkvp, qb, kvb, N, NB,
      tmp, bfill, ofl, ofl_cnt, rowptr, packed, nbuck, shift, CAP);

  // fused: attention + tail (msg stays in LDS)
  k_attail<<<NB, 256, 0, stream>>>(
      x, flag, qb, kvb, packed, rowptr, wop, w1p, w2p, pc, d_out, N, th);
}

// Round 9
// 232.664 us; speedup vs baseline: 1.1638x; 1.1638x over previous
//
#include <hip/hip_runtime.h>
#include <hip/hip_bf16.h>

typedef short bf16x8 __attribute__((ext_vector_type(8)));
typedef float f32x4 __attribute__((ext_vector_type(4)));
typedef _Float16 f16x2 __attribute__((ext_vector_type(2)));
typedef _Float16 f16x8 __attribute__((ext_vector_type(8)));

// ---------- helpers ----------
static __device__ __forceinline__ float bf2f(unsigned short u) {
  return __uint_as_float(((unsigned)u) << 16);
}
static __device__ __forceinline__ unsigned short f2bf(float f) {
  unsigned u = __float_as_uint(f);
  u += 0x7fffu + ((u >> 16) & 1u);   // RNE
  return (unsigned short)(u >> 16);
}
static __device__ __forceinline__ unsigned packbf(float a, float b) {
  return (unsigned)f2bf(a) | ((unsigned)f2bf(b) << 16);
}
// tanh-gelu via hardware exp: tanh(z) = 1 - 2/(exp(2z)+1)
static __device__ __forceinline__ float gelu_fast(float a) {
  float u = a * (1.5957691216057308f + 0.07135481627f * a * a);  // 2z
  float e = __expf(u);
  float r = __builtin_amdgcn_rcpf(e + 1.f);
  return a - a * r;   // a*(1 - 1/(e+1)) = 0.5a(1+tanh z)
}
static __device__ __forceinline__ float dot2(f16x2 a, f16x2 b, float c) {
#if __has_builtin(__builtin_amdgcn_fdot2)
  return __builtin_amdgcn_fdot2(a, b, c, false);
#else
  return c + (float)a[0] * (float)b[0] + (float)a[1] * (float)b[1];
#endif
}
template <typename T, typename F>
static __device__ __forceinline__ T bcast(F v) {
  union { F f; T t; } u; u.f = v; return u.t;
}
// f16 bits -> e5m2 byte (RNE truncation of top byte)
static __device__ __forceinline__ unsigned char f16_to_bf8(_Float16 h) {
  unsigned short b = bcast<unsigned short>(h);
  unsigned t = (unsigned)b + 0x7Fu + ((b >> 8) & 1u);
  return (unsigned char)(t >> 8);
}
// inline dtype detect: every wave samples the same 1024 words of x (identical
// result everywhere) -- replaces the k_detect launch + flag buffer.
static __device__ __forceinline__ int detect_isf(const unsigned* __restrict__ x) {
  const int lane = threadIdx.x & 63;
  int good = 0;
  #pragma unroll
  for (int i = 0; i < 16; ++i) {
    float v = fabsf(bf2f((unsigned short)(x[lane + i * 64] & 0xFFFFu)));
    good += (v >= 0.0009765625f && v <= 32.0f) ? 1 : 0;
  }
  #pragma unroll
  for (int o = 1; o < 64; o <<= 1) good += __shfl_xor(good, o);
  return (good < 512) ? 1 : 0;   // 1 => inputs are f32
}

// param-block element offsets (bf16 canonical)
#define PC_G1   0
#define PC_B1   128
#define PC_WQ   256
#define PC_BQ   16640
#define PC_WK   16768
#define PC_BK   33152
#define PC_WV   33280
#define PC_BV   49664
#define PC_EB   49792
#define PC_WO   49824
#define PC_BO   66208
#define PC_G2   66336
#define PC_B2   66464
#define PC_W1   66592
#define PC_B1F  99360
#define PC_W2   99616
#define PC_B2F  132384
#define PC_TOT  132512
#define B_CONV  518   // ceil(PC_TOT/256)

#define MAXBUCK 512
#define OFLCAP  8192

// ---------- fused: param prep (+weight repack) || binned edge scatter ----------
struct PP { const void* p[17]; };

static __device__ __forceinline__ unsigned short rdw(const void* p, int isf, int idx) {
  return isf ? f2bf(((const float*)p)[idx]) : ((const unsigned short*)p)[idx];
}
static __device__ __forceinline__ void pack_one(
    const void* w, int isf, int rs, int K, int ntl_n,
    unsigned short* __restrict__ dst, int nt0, int idx)
{
  int k32 = K >> 5;
  if (idx >= ntl_n * k32 * 64) return;
  int lane = idx & 63;
  int ks = (idx >> 6) % k32;
  int ntl = idx / (64 * k32);
  int m = lane & 15, q = lane >> 4;
  int col = ntl * 16 + m;
  int kb = ks * 32 + q * 8;
  unsigned short tmp[8];
  #pragma unroll
  for (int j = 0; j < 8; ++j) tmp[j] = rdw(w, isf, (kb + j) * rs + col);
  *(uint4*)&dst[(size_t)(((nt0 + ntl) * k32 + ks) * 64 + lane) * 8] = *(const uint4*)tmp;
}

// Blocks [0, B_CONV+66): param conversion + weight repack.
// Blocks [B_CONV+66, +bb): binned scatter of edges into fixed-capacity bucket
// regions of tmp (bucket b owns [b*CAP, (b+1)*CAP)); per-block LDS histogram +
// one global atomic per (block,bucket) reserves a contiguous run. Rare overflow
// (run past CAP) spills per-edge to ofl[] -- exactness for any input.
__global__ __launch_bounds__(256) void k_prep(
    PP pp, const unsigned* __restrict__ xdet, unsigned short* __restrict__ pc,
    unsigned short* __restrict__ wqkvp, unsigned short* __restrict__ wop,
    unsigned short* __restrict__ w1p, unsigned short* __restrict__ w2p,
    unsigned short* __restrict__ bqkvb,
    const int* __restrict__ ei, const int* __restrict__ et,
    int* __restrict__ bfill, unsigned* __restrict__ tmp,
    int2* __restrict__ ofl, int* __restrict__ ofl_cnt,
    int E, int nbuck, int shift, int CAP, int bb)
{
  __shared__ int cnt[MAXBUCK];
  const int b = blockIdx.x, tid = threadIdx.x;
  if (b < B_CONV + 66) {
    const int isf = detect_isf(xdet);
    if (b < B_CONV) {
      const int offs[18] = {PC_G1,PC_B1,PC_WQ,PC_BQ,PC_WK,PC_BK,PC_WV,PC_BV,PC_EB,
                            PC_WO,PC_BO,PC_G2,PC_B2,PC_W1,PC_B1F,PC_W2,PC_B2F,PC_TOT};
      int i = b * 256 + tid;
      if (i >= PC_TOT) return;
      int s = 0;
      while (i >= offs[s + 1]) ++s;
      pc[i] = rdw(pp.p[s], isf, i - offs[s]);
    } else if (b < B_CONV + 8)  pack_one(pp.p[2],  isf, 128, 128, 8,  wqkvp, 0,  (b - B_CONV) * 256 + tid);
    else if (b < B_CONV + 16)   pack_one(pp.p[4],  isf, 128, 128, 8,  wqkvp, 8,  (b - B_CONV - 8) * 256 + tid);
    else if (b < B_CONV + 24)   pack_one(pp.p[6],  isf, 128, 128, 8,  wqkvp, 16, (b - B_CONV - 16) * 256 + tid);
    else if (b < B_CONV + 32)   pack_one(pp.p[9],  isf, 128, 128, 8,  wop,   0,  (b - B_CONV - 24) * 256 + tid);
    else if (b < B_CONV + 48)   pack_one(pp.p[13], isf, 256, 128, 16, w1p,   0,  (b - B_CONV - 32) * 256 + tid);
    else if (b < B_CONV + 64)   pack_one(pp.p[15], isf, 128, 256, 8,  w2p,   0,  (b - B_CONV - 48) * 256 + tid);
    else {
      int i = (b - B_CONV - 64) * 256 + tid;
      if (i < 384) {
        int s = i >> 7, c = i & 127;
        const void* src = (s == 0) ? pp.p[3] : ((s == 1) ? pp.p[5] : pp.p[7]);
        bqkvb[i] = rdw(src, isf, c);
      }
    }
    return;
  }

  // ---- binned scatter ----
  const int bsb = b - (B_CONV + 66);
  const unsigned lowmask = (1u << shift) - 1u;
  for (int base = bsb * 4096; base < E; base += bb * 4096) {
    for (int i = tid; i < nbuck; i += 256) cnt[i] = 0;
    __syncthreads();
    unsigned pk[16]; int bk[16];
    #pragma unroll
    for (int u = 0; u < 16; ++u) {
      int e = base + u * 256 + tid;
      if (e < E) {
        unsigned s = (unsigned)ei[e];
        unsigned d = (unsigned)ei[E + e];
        unsigned t = (unsigned)et[e];
        int bq = min((int)(d >> shift), nbuck - 1);
        pk[u] = s | (t << 18) | ((d & lowmask) << 20);
        bk[u] = bq;
        atomicAdd(&cnt[bq], 1);
      } else bk[u] = -1;
    }
    __syncthreads();
    for (int i = tid; i < nbuck; i += 256) {
      int c = cnt[i];
      cnt[i] = c ? i * CAP + atomicAdd(&bfill[i], c) : 0;
    }
    __syncthreads();
    #pragma unroll
    for (int u = 0; u < 16; ++u) {
      if (bk[u] >= 0) {
        int pos = atomicAdd(&cnt[bk[u]], 1);
        if (pos < (bk[u] + 1) * CAP) {
          tmp[pos] = pk[u];
        } else {
          int oi = atomicAdd(ofl_cnt, 1);
          if (oi < OFLCAP) { int2 o; o.x = (int)pk[u]; o.y = bk[u]; ofl[oi] = o; }
        }
      }
    }
    __syncthreads();
  }
}

// ---------- fused: LN1+QKV GEMM || per-bucket CSR sort ----------
// Blocks [0, NB): LN1 + QKV via MFMA -> qb (f16) + kvb (e5m2, row = [k 8h x 16B][v ...]).
// Blocks [NB, NB+nbuck): sort bucket region of tmp into CSR order (packed) and
// emit rowptr; bucket base in packed = running sum of bfill (on-the-fly reduce).
__global__ __launch_bounds__(256) void k_lnqkv(
    const void* __restrict__ xin,
    const unsigned short* __restrict__ pc,
    const unsigned short* __restrict__ bias,
    const unsigned short* __restrict__ wpack,
    _Float16* __restrict__ qb, unsigned char* __restrict__ kvb, int N, int NB,
    const unsigned* __restrict__ tmp, const int* __restrict__ bfill,
    const int2* __restrict__ ofl, const int* __restrict__ ofl_cnt,
    int* __restrict__ rowptr, unsigned* __restrict__ packed,
    int nbuck, int shift, int CAP)
{
  __shared__ __align__(16) char shraw[64 * 136 * 2];   // 17408 B arena
  const int tid = threadIdx.x, lane = tid & 63, wv = tid >> 6;

  if ((int)blockIdx.x >= NB) {
    // ---- bucketsort ----
    int* cnt = (int*)shraw;                  // 1024 ints
    int* cur = (int*)(shraw + 4096);         // 1024 ints
    int* ws  = (int*)(shraw + 8192);         // 4 ints
    int* rs  = (int*)(shraw + 8224);         // 8 ints
    int* carry_s = (int*)(shraw + 8256);
    const int bw = 1 << shift;
    const int b2 = (int)blockIdx.x - NB;
    const int n0 = b2 << shift;

    int s_before = 0, s_all = 0;
    for (int i = tid; i < nbuck; i += 256) {
      int v = bfill[i];
      s_all += v;
      if (i < b2) s_before += v;
    }
    #pragma unroll
    for (int o = 1; o < 64; o <<= 1) {
      s_before += __shfl_xor(s_before, o);
      s_all    += __shfl_xor(s_all, o);
    }
    if (lane == 0) { rs[wv] = s_before; rs[4 + wv] = s_all; }
    for (int i = tid; i < bw; i += 256) cnt[i] = 0;
    if (tid == 0) *carry_s = 0;
    __syncthreads();
    const int beg = rs[0] + rs[1] + rs[2] + rs[3];
    const int tot = rs[4] + rs[5] + rs[6] + rs[7];
    const int stored = min(bfill[b2], CAP);
    const int tbase = b2 * CAP;
    if (b2 == 0 && tid == 0) rowptr[N] = tot;
    const int onum = min(*ofl_cnt, OFLCAP);

    for (int i = tid; i < stored; i += 256)
      atomicAdd(&cnt[(tmp[tbase + i] >> 20) & (unsigned)(bw - 1)], 1);
    for (int i = tid; i < onum; i += 256) {
      int2 o = ofl[i];
      if (o.y == b2) atomicAdd(&cnt[(((unsigned)o.x) >> 20) & (unsigned)(bw - 1)], 1);
    }
    __syncthreads();
    for (int base = 0; base < bw; base += 256) {
      int i = base + tid;
      int v = (i < bw) ? cnt[i] : 0;
      int s = v;
      #pragma unroll
      for (int o = 1; o < 64; o <<= 1) { int t = __shfl_up(s, o); if (lane >= o) s += t; }
      if (lane == 63) ws[wv] = s;
      int c = *carry_s;
      __syncthreads();
      int off = c;
      for (int k = 0; k < wv; ++k) off += ws[k];
      if (i < bw) {
        int excl = beg + off + s - v;
        cur[i] = excl;
        if (n0 + i < N) rowptr[n0 + i] = excl;
      }
      __syncthreads();
      if (tid == 0) *carry_s = c + ws[0] + ws[1] + ws[2] + ws[3];
      __syncthreads();
    }
    for (int i = tid; i < stored; i += 256) {
      unsigned pk = tmp[tbase + i];
      int dl = (int)((pk >> 20) & (unsigned)(bw - 1));
      int pos = atomicAdd(&cur[dl], 1);
      packed[pos] = pk;   // dlow bits stay in 20+; attn masks type with &3
    }
    for (int i = tid; i < onum; i += 256) {
      int2 o = ofl[i];
      if (o.y == b2) {
        unsigned pk = (unsigned)o.x;
        int dl = (int)((pk >> 20) & (unsigned)(bw - 1));
        int pos = atomicAdd(&cur[dl], 1);
        packed[pos] = pk;
      }
    }
    return;
  }

  // ---- LN1 + QKV ----
  unsigned short* H = (unsigned short*)shraw;   // 64 x 136
  const int row0 = blockIdx.x * 64;
  const int isf = detect_isf((const unsigned*)xin);
  {
    const int rl = tid >> 2, c0 = (tid & 3) * 32;
    const int r = row0 + rl;
    float xv[32];
    if (r < N) {
      if (isf) {
        const float4* xp = (const float4*)((const float*)xin + (size_t)r * 128 + c0);
        #pragma unroll
        for (int u = 0; u < 8; ++u) {
          float4 f = xp[u];
          xv[u*4] = f.x; xv[u*4+1] = f.y; xv[u*4+2] = f.z; xv[u*4+3] = f.w;
        }
      } else {
        const uint4* xp = (const uint4*)((const unsigned short*)xin + (size_t)r * 128 + c0);
        #pragma unroll
        for (int u = 0; u < 4; ++u) {
          uint4 w = xp[u];
          unsigned ww[4] = {w.x, w.y, w.z, w.w};
          #pragma unroll
          for (int p = 0; p < 4; ++p) {
            xv[u*8 + 2*p]     = bf2f((unsigned short)ww[p]);
            xv[u*8 + 2*p + 1] = bf2f((unsigned short)(ww[p] >> 16));
          }
        }
      }
    } else {
      #pragma unroll
      for (int u = 0; u < 32; ++u) xv[u] = 0.f;
    }
    float s = 0.f, s2 = 0.f;
    #pragma unroll
    for (int u = 0; u < 32; ++u) { s += xv[u]; s2 += xv[u] * xv[u]; }
    s += __shfl_xor(s, 1); s2 += __shfl_xor(s2, 1);
    s += __shfl_xor(s, 2); s2 += __shfl_xor(s2, 2);
    float mean = s * (1.f / 128.f);
    float var  = fmaxf(s2 * (1.f / 128.f) - mean * mean, 0.f);
    float inv  = rsqrtf(var + 1e-5f);
    unsigned short hb[32];
    #pragma unroll
    for (int u = 0; u < 32; ++u) {
      int c = c0 + u;
      hb[u] = f2bf((xv[u] - mean) * inv * bf2f(pc[PC_G1 + c]) + bf2f(pc[PC_B1 + c]));
    }
    uint4* hp = (uint4*)&H[rl * 136 + c0];
    #pragma unroll
    for (int u = 0; u < 4; ++u) hp[u] = ((const uint4*)hb)[u];
  }
  __syncthreads();

  const int wave = wv;
  const int m = lane & 15, q = lane >> 4;
  bf16x8 a[16];
  #pragma unroll
  for (int rt = 0; rt < 4; ++rt) {
    const unsigned short* hrow = &H[(rt * 16 + m) * 136 + q * 8];
    #pragma unroll
    for (int ks = 0; ks < 4; ++ks) a[rt*4+ks] = *(const bf16x8*)&hrow[ks * 32];
  }
  const f32x4 z = {0.f, 0.f, 0.f, 0.f};
  #pragma unroll
  for (int p = 0; p < 3; ++p) {
    bf16x8 bfr[8];
    #pragma unroll
    for (int tt = 0; tt < 2; ++tt)
      #pragma unroll
      for (int ks = 0; ks < 4; ++ks)
        bfr[tt*4+ks] = *(const bf16x8*)&wpack[(size_t)(((wave*6 + 2*p + tt)*4 + ks)*64 + lane)*8];
    f32x4 c[4][2];
    #pragma unroll
    for (int rt = 0; rt < 4; ++rt) { c[rt][0] = z; c[rt][1] = z; }
    #pragma unroll
    for (int rt = 0; rt < 4; ++rt)
      #pragma unroll
      for (int ks = 0; ks < 4; ++ks) {
        c[rt][0] = __builtin_amdgcn_mfma_f32_16x16x32_bf16(a[rt*4+ks], bfr[ks],   c[rt][0], 0, 0, 0);
        c[rt][1] = __builtin_amdgcn_mfma_f32_16x16x32_bf16(a[rt*4+ks], bfr[4+ks], c[rt][1], 0, 0, 0);
      }
    #pragma unroll
    for (int tt = 0; tt < 2; ++tt) {
      int jj = (wave*6 + 2*p + tt) * 16 + m;
      float bv = bf2f(bias[jj]);
      #pragma unroll
      for (int rt = 0; rt < 4; ++rt)
        #pragma unroll
        for (int rr = 0; rr < 4; ++rr) {
          int row = row0 + rt*16 + q*4 + rr;
          if (row < N) {
            _Float16 hv = (_Float16)(c[rt][tt][rr] + bv);
            if (jj < 128) {
              qb[(size_t)row * 128 + jj] = hv;
            } else if (jj < 256) {
              int cc = jj - 128, h = cc >> 4, d = cc & 15;
              kvb[(size_t)row * 256 + h * 16 + d] = f16_to_bf8(hv);
            } else {
              int cc = jj - 256, h = cc >> 4, d = cc & 15;
              kvb[(size_t)row * 256 + 128 + h * 16 + d] = f16_to_bf8(hv);
            }
          }
        }
    }
  }
}

// ---------- attention: wave-per-node, lane=(edge,head), e5m2 KV, perm decode ----------
__global__ __launch_bounds__(256) void k_attn(
    const _Float16* __restrict__ qb, const unsigned char* __restrict__ kvb,
    const unsigned* __restrict__ packed, const int* __restrict__ rowptr,
    const unsigned short* __restrict__ pc, unsigned short* __restrict__ msgb,
    int N, int th)
{
  __shared__ float ebs[64];
  const int tid = threadIdx.x, lane = tid & 63, wave = tid >> 6;
  if (tid < th) ebs[tid] = bf2f(pc[PC_EB + tid]);
  __syncthreads();
  const int n = blockIdx.x * 4 + wave;
  if (n >= N) return;
  const int h = lane & 7, el = lane >> 3;

  f16x8 qa, qc;
  {
    const _Float16* qp = qb + (size_t)n * 128 + h * 16;
    qa = *(const f16x8*)qp;
    qc = *(const f16x8*)(qp + 8);
  }
  const int beg = rowptr[n], end = rowptr[n + 1];
  float l = 0.f;
  f16x8 accA = {0, 0, 0, 0, 0, 0, 0, 0};
  f16x8 accB = {0, 0, 0, 0, 0, 0, 0, 0};

  if (beg < end) {
    const int last = end - 1;
    unsigned pk = packed[min(beg + el, last)];
    const unsigned char* kp = kvb + (size_t)(pk & 0x3FFFF) * 256 + h * 16;
    uint4 kw = *(const uint4*)kp;
    uint4 vw = *(const uint4*)(kp + 128);

    for (int base = beg; base < end; base += 8) {
      unsigned pk2 = 0; uint4 kw2, vw2;
      const bool more = (base + 8) < end;   // wave-uniform
      if (more) {
        pk2 = packed[min(base + 8 + el, last)];
        const unsigned char* kp2 = kvb + (size_t)(pk2 & 0x3FFFF) * 256 + h * 16;
        kw2 = *(const uint4*)kp2;
        vw2 = *(const uint4*)(kp2 + 128);
      }

      // decode k (16 e5m2 bytes -> 8 f16x2 via v_perm) and dot with q
      float s = 0.f;
      {
        unsigned kd[4] = {kw.x, kw.y, kw.z, kw.w};
        #pragma unroll
        for (int j = 0; j < 2; ++j) {
          f16x2 klo = bcast<f16x2>(__builtin_amdgcn_perm(0u, kd[j], 0x010c000cu));
          f16x2 khi = bcast<f16x2>(__builtin_amdgcn_perm(0u, kd[j], 0x030c020cu));
          f16x2 a0 = {qa[4*j], qa[4*j+1]}, a1 = {qa[4*j+2], qa[4*j+3]};
          s = dot2(a0, klo, s);
          s = dot2(a1, khi, s);
        }
        #pragma unroll
        for (int j = 0; j < 2; ++j) {
          f16x2 klo = bcast<f16x2>(__builtin_amdgcn_perm(0u, kd[2+j], 0x010c000cu));
          f16x2 khi = bcast<f16x2>(__builtin_amdgcn_perm(0u, kd[2+j], 0x030c020cu));
          f16x2 a0 = {qc[4*j], qc[4*j+1]}, a1 = {qc[4*j+2], qc[4*j+3]};
          s = dot2(a0, klo, s);
          s = dot2(a1, khi, s);
        }
      }
      float sc = fminf(s * 0.25f + ebs[((pk >> 18) & 3u) * 8 + h], 80.f);
      float pe = (base + el < end) ? __expf(sc) : 0.f;
      l += pe;
      _Float16 pf = (_Float16)pe;
      f16x8 p8 = {pf, pf, pf, pf, pf, pf, pf, pf};
      // decode v and accumulate
      {
        unsigned vd[4] = {vw.x, vw.y, vw.z, vw.w};
        union { unsigned u[4]; f16x8 v; } va, vb;
        va.u[0] = __builtin_amdgcn_perm(0u, vd[0], 0x010c000cu);
        va.u[1] = __builtin_amdgcn_perm(0u, vd[0], 0x030c020cu);
        va.u[2] = __builtin_amdgcn_perm(0u, vd[1], 0x010c000cu);
        va.u[3] = __builtin_amdgcn_perm(0u, vd[1], 0x030c020cu);
        vb.u[0] = __builtin_amdgcn_perm(0u, vd[2], 0x010c000cu);
        vb.u[1] = __builtin_amdgcn_perm(0u, vd[2], 0x030c020cu);
        vb.u[2] = __builtin_amdgcn_perm(0u, vd[3], 0x010c000cu);
        vb.u[3] = __builtin_amdgcn_perm(0u, vd[3], 0x030c020cu);
        accA += p8 * va.v;
        accB += p8 * vb.v;
      }

      if (more) { pk = pk2; kw = kw2; vw = vw2; }
    }
  }

  #pragma unroll
  for (int mask = 8; mask <= 32; mask <<= 1) {
    l += __shfl_xor(l, mask);
    int2 ai = bcast<int2>(accA), bi = bcast<int2>(accB);
    int2 as, bs;
    as.x = __shfl_xor(ai.x, mask); as.y = __shfl_xor(ai.y, mask);
    bs.x = __shfl_xor(bi.x, mask); bs.y = __shfl_xor(bi.y, mask);
    accA += bcast<f16x8>(as);
    accB += bcast<f16x8>(bs);
  }
  if (el == 0) {
    float inv = 1.f / (l + 1e-9f);
    unsigned o[8];
    #pragma unroll
    for (int j = 0; j < 4; ++j)
      o[j] = packbf((float)accA[2*j] * inv, (float)accA[2*j+1] * inv);
    #pragma unroll
    for (int j = 0; j < 4; ++j)
      o[4+j] = packbf((float)accB[2*j] * inv, (float)accB[2*j+1] * inv);
    uint4* dst = (uint4*)(msgb + (size_t)n * 128 + h * 16);
    uint4 d0 = {o[0], o[1], o[2], o[3]}, d1 = {o[4], o[5], o[6], o[7]};
    dst[0] = d0; dst[1] = d1;
  }
}

// ---------- fused tail: msg@wo+res -> LN2 -> FFN1(gelu) -> FFN2+res -> out ----------
__global__ __launch_bounds__(256) void k_tail(
    const void* __restrict__ xin,
    const unsigned short* __restrict__ msgb,
    const unsigned short* __restrict__ wop, const unsigned short* __restrict__ w1p,
    const unsigned short* __restrict__ w2p, const unsigned short* __restrict__ pc,
    void* __restrict__ out, int N)
{
  __shared__ unsigned short x1s[64 * 136];
  __shared__ unsigned short hts[64 * 264];   // LN2 phase: stride 136; FFN1-out: stride 264
  const int tid = threadIdx.x;
  const int row0 = blockIdx.x * 64;
  const int isf = detect_isf((const unsigned*)xin);
  const int wave = tid >> 6, lane = tid & 63;
  const int m = lane & 15, q = lane >> 4;
  const f32x4 z = {0.f, 0.f, 0.f, 0.f};

  bf16x8 b1[8];
  #pragma unroll
  for (int tt = 0; tt < 2; ++tt)
    #pragma unroll
    for (int ks = 0; ks < 4; ++ks)
      b1[tt*4+ks] = *(const bf16x8*)&wop[(size_t)(((2*wave + tt)*4 + ks)*64 + lane)*8];
  bf16x8 a1[16];
  #pragma unroll
  for (int rt = 0; rt < 4; ++rt) {
    const unsigned short* ap = msgb + (size_t)min(row0 + rt*16 + m, N - 1) * 128 + q * 8;
    #pragma unroll
    for (int ks = 0; ks < 4; ++ks) a1[rt*4+ks] = *(const bf16x8*)&ap[ks * 32];
  }

  {
    int rl = tid >> 2, c0 = (tid & 3) * 32;
    int r = row0 + rl;
    unsigned short hb[32];
    if (r < N) {
      if (isf) {
        const float4* xp = (const float4*)((const float*)xin + (size_t)r * 128 + c0);
        #pragma unroll
        for (int u = 0; u < 8; ++u) {
          float4 f = xp[u];
          hb[u*4] = f2bf(f.x); hb[u*4+1] = f2bf(f.y);
          hb[u*4+2] = f2bf(f.z); hb[u*4+3] = f2bf(f.w);
        }
      } else {
        const uint4* xp = (const uint4*)((const unsigned short*)xin + (size_t)r * 128 + c0);
        #pragma unroll
        for (int u = 0; u < 4; ++u) ((uint4*)hb)[u] = xp[u];
      }
    } else {
      #pragma unroll
      for (int u = 0; u < 32; ++u) hb[u] = 0;
    }
    #pragma unroll
    for (int u = 0; u < 4; ++u) ((uint4*)&x1s[rl * 136 + c0])[u] = ((const uint4*)hb)[u];
  }
  __syncthreads();

  // GEMM1: attn_out @ wo (+bias +residual) -> x1s
  {
    f32x4 c[4][2];
    #pragma unroll
    for (int rt = 0; rt < 4; ++rt) { c[rt][0] = z; c[rt][1] = z; }
    #pragma unroll
    for (int rt = 0; rt < 4; ++rt)
      #pragma unroll
      for (int ks = 0; ks < 4; ++ks) {
        c[rt][0] = __builtin_amdgcn_mfma_f32_16x16x32_bf16(a1[rt*4+ks], b1[ks],   c[rt][0], 0, 0, 0);
        c[rt][1] = __builtin_amdgcn_mfma_f32_16x16x32_bf16(a1[rt*4+ks], b1[4+ks], c[rt][1], 0, 0, 0);
      }
    #pragma unroll
    for (int tt = 0; tt < 2; ++tt) {
      int col = (2*wave + tt) * 16 + m;
      float bv = bf2f(pc[PC_BO + col]);
      #pragma unroll
      for (int rt = 0; rt < 4; ++rt)
        #pragma unroll
        for (int rr = 0; rr < 4; ++rr) {
          int rl = rt*16 + q*4 + rr;
          float o = c[rt][tt][rr] + bv + bf2f(x1s[rl * 136 + col]);
          x1s[rl * 136 + col] = f2bf(o);
        }
    }
  }
  __syncthreads();

  bf16x8 b2[16];
  #pragma unroll
  for (int u = 0; u < 4; ++u)
    #pragma unroll
    for (int ks = 0; ks < 4; ++ks)
      b2[u*4+ks] = *(const bf16x8*)&w1p[(size_t)(((4*wave + u)*4 + ks)*64 + lane)*8];

  // LN2
  {
    int rl = tid >> 2, c0 = (tid & 3) * 32;
    unsigned short hb[32];
    #pragma unroll
    for (int u = 0; u < 4; ++u) ((uint4*)hb)[u] = *(const uint4*)&x1s[rl * 136 + c0 + u * 8];
    float xv[32];
    #pragma unroll
    for (int u = 0; u < 32; ++u) xv[u] = bf2f(hb[u]);
    float s = 0.f, s2 = 0.f;
    #pragma unroll
    for (int u = 0; u < 32; ++u) { s += xv[u]; s2 += xv[u] * xv[u]; }
    s += __shfl_xor(s, 1); s2 += __shfl_xor(s2, 1);
    s += __shfl_xor(s, 2); s2 += __shfl_xor(s2, 2);
    float mean = s * (1.f / 128.f);
    float var  = fmaxf(s2 * (1.f / 128.f) - mean * mean, 0.f);
    float inv  = rsqrtf(var + 1e-5f);
    #pragma unroll
    for (int u = 0; u < 32; ++u) {
      int c = c0 + u;
      hb[u] = f2bf((xv[u] - mean) * inv * bf2f(pc[PC_G2 + c]) + bf2f(pc[PC_B2 + c]));
    }
    #pragma unroll
    for (int u = 0; u < 4; ++u) ((uint4*)&hts[rl * 136 + c0])[u] = ((const uint4*)hb)[u];
  }
  __syncthreads();

  bf16x8 a2[16];
  #pragma unroll
  for (int rt = 0; rt < 4; ++rt) {
    const unsigned short* hp = &hts[(rt*16 + m) * 136 + q * 8];
    #pragma unroll
    for (int ks = 0; ks < 4; ++ks) a2[rt*4+ks] = *(const bf16x8*)&hp[ks * 32];
  }
  __syncthreads();   // hts about to be reused (stride 264) as FFN1 output

  #pragma unroll
  for (int p = 0; p < 2; ++p) {
    f32x4 c[4][2];
    #pragma unroll
    for (int rt = 0; rt < 4; ++rt) { c[rt][0] = z; c[rt][1] = z; }
    #pragma unroll
    for (int rt = 0; rt < 4; ++rt)
      #pragma unroll
      for (int ks = 0; ks < 4; ++ks) {
        c[rt][0] = __builtin_amdgcn_mfma_f32_16x16x32_bf16(a2[rt*4+ks], b2[(2*p)*4+ks],   c[rt][0], 0, 0, 0);
        c[rt][1] = __builtin_amdgcn_mfma_f32_16x16x32_bf16(a2[rt*4+ks], b2[(2*p+1)*4+ks], c[rt][1], 0, 0, 0);
      }
    #pragma unroll
    for (int tt = 0; tt < 2; ++tt) {
      int col = (4*wave + 2*p + tt) * 16 + m;
      float bv = bf2f(pc[PC_B1F + col]);
      #pragma unroll
      for (int rt = 0; rt < 4; ++rt)
        #pragma unroll
        for (int rr = 0; rr < 4; ++rr)
          hts[(rt*16 + q*4 + rr) * 264 + col] = f2bf(gelu_fast(c[rt][tt][rr] + bv));
    }
  }

  bf16x8 b3[16];
  #pragma unroll
  for (int tt = 0; tt < 2; ++tt)
    #pragma unroll
    for (int ks = 0; ks < 8; ++ks)
      b3[tt*8+ks] = *(const bf16x8*)&w2p[(size_t)(((2*wave + tt)*8 + ks)*64 + lane)*8];
  __syncthreads();

  #pragma unroll
  for (int rt = 0; rt < 4; ++rt) {
    bf16x8 a3[8];
    const unsigned short* tp = &hts[(rt*16 + m) * 264 + q * 8];
    #pragma unroll
    for (int ks = 0; ks < 8; ++ks) a3[ks] = *(const bf16x8*)&tp[ks * 32];
    f32x4 c0 = z, c1 = z;
    #pragma unroll
    for (int ks = 0; ks < 8; ++ks) {
      c0 = __builtin_amdgcn_mfma_f32_16x16x32_bf16(a3[ks], b3[ks],   c0, 0, 0, 0);
      c1 = __builtin_amdgcn_mfma_f32_16x16x32_bf16(a3[ks], b3[8+ks], c1, 0, 0, 0);
    }
    #pragma unroll
    for (int tt = 0; tt < 2; ++tt) {
      f32x4 cc = tt ? c1 : c0;
      int col = (2*wave + tt) * 16 + m;
      float bv = bf2f(pc[PC_B2F + col]);
      #pragma unroll
      for (int rr = 0; rr < 4; ++rr) {
        int rl = rt*16 + q*4 + rr;
        int row = row0 + rl;
        if (row < N) {
          float o = cc[rr] + bv + bf2f(x1s[rl * 136 + col]);
          if (isf) ((float*)out)[(size_t)row * 128 + col] = o;
          else     ((unsigned short*)out)[(size_t)row * 128 + col] = f2bf(o);
        }
      }
    }
  }
}

// ---------- launch ----------
extern "C" void kernel_launch(void* const* d_in, const int* in_sizes, int n_in,
                              void* d_out, int out_size, void* d_ws, size_t ws_size,
                              hipStream_t stream)
{
  const void* x = d_in[0];
  const int* ei = (const int*)d_in[1];
  const int* et = (const int*)d_in[2];
  const int N = in_sizes[0] / 128;
  const int E = in_sizes[2];
  int th = in_sizes[13];
  if (th > 64) th = 64;

  int shift = 7;
  while ((((N + (1 << shift) - 1) >> shift) > MAXBUCK) && shift < 10) ++shift;
  const int nbuck = (N + (1 << shift) - 1) >> shift;
  const int CAP = ((2 * (E / nbuck) + 512) + 63) & ~63;   // >>10 sigma headroom

  char* ws = (char*)d_ws;
  size_t off = 0;
  auto alloc = [&](size_t bytes) -> void* {
    void* p = ws + off; off += (bytes + 255) & ~(size_t)255; return p;
  };
  unsigned short* pc = (unsigned short*)alloc((size_t)PC_TOT * 2);
  _Float16* qb  = (_Float16*)alloc((size_t)N * 128 * 2);
  unsigned char* kvb = (unsigned char*)alloc((size_t)N * 256);
  unsigned* packed = (unsigned*)alloc((size_t)E * 4);
  unsigned* tmp = (unsigned*)alloc((size_t)nbuck * CAP * 4);
  int2* ofl = (int2*)alloc((size_t)OFLCAP * 8);
  int* rowptr = (int*)alloc((size_t)(N + 1) * 4);
  unsigned short* msgb = (unsigned short*)alloc((size_t)N * 128 * 2);
  unsigned short* wqkvp = (unsigned short*)alloc((size_t)128 * 384 * 2);
  unsigned short* wop   = (unsigned short*)alloc((size_t)128 * 128 * 2);
  unsigned short* w1p   = (unsigned short*)alloc((size_t)128 * 256 * 2);
  unsigned short* w2p   = (unsigned short*)alloc((size_t)256 * 128 * 2);
  unsigned short* bqkvb = (unsigned short*)alloc(384 * 2);
  size_t zoff = off;
  int* bfill   = (int*)alloc((size_t)MAXBUCK * 4);
  int* ofl_cnt = (int*)alloc(4);
  hipMemsetAsync(ws + zoff, 0, off - zoff, stream);

  PP pp;
  for (int i = 0; i < 17; ++i) pp.p[i] = d_in[5 + i];

  const int NB = (N + 63) / 64;
  const int bb = (E + 4095) / 4096;

  // fused: param prep || binned edge scatter (isf computed inline per wave)
  k_prep<<<B_CONV + 66 + bb, 256, 0, stream>>>(
      pp, (const unsigned*)x, pc, wqkvp, wop, w1p, w2p, bqkvb,
      ei, et, bfill, tmp, ofl, ofl_cnt, E, nbuck, shift, CAP, bb);

  // fused: LN1+QKV || per-bucket CSR sort
  k_lnqkv<<<NB + nbuck, 256, 0, stream>>>(
      x, pc, bqkvb, wqkvp, qb, kvb, N, NB,
      tmp, bfill, ofl, ofl_cnt, rowptr, packed, nbuck, shift, CAP);

  // attention (high-occupancy, 512B LDS) -> msgb
  k_attn<<<(N + 3) / 4, 256, 0, stream>>>(qb, kvb, packed, rowptr, pc, msgb, N, th);

  // fused tail
  k_tail<<<NB, 256, 0, stream>>>(x, msgb, wop, w1p, w2p, pc, d_out, N);
}

// Round 11
// 225.991 us; speedup vs baseline: 1.1982x; 1.0295x over previous
//
#include <hip/hip_runtime.h>
#include <hip/hip_bf16.h>

typedef short bf16x8 __attribute__((ext_vector_type(8)));
typedef float f32x4 __attribute__((ext_vector_type(4)));
typedef _Float16 f16x2 __attribute__((ext_vector_type(2)));
typedef _Float16 f16x8 __attribute__((ext_vector_type(8)));

// ---------- helpers ----------
static __device__ __forceinline__ float bf2f(unsigned short u) {
  return __uint_as_float(((unsigned)u) << 16);
}
static __device__ __forceinline__ unsigned short f2bf(float f) {
  unsigned u = __float_as_uint(f);
  u += 0x7fffu + ((u >> 16) & 1u);   // RNE
  return (unsigned short)(u >> 16);
}
static __device__ __forceinline__ unsigned packbf(float a, float b) {
  return (unsigned)f2bf(a) | ((unsigned)f2bf(b) << 16);
}
// tanh-gelu via hardware exp: tanh(z) = 1 - 2/(exp(2z)+1)
static __device__ __forceinline__ float gelu_fast(float a) {
  float u = a * (1.5957691216057308f + 0.07135481627f * a * a);  // 2z
  float e = __expf(u);
  float r = __builtin_amdgcn_rcpf(e + 1.f);
  return a - a * r;   // a*(1 - 1/(e+1)) = 0.5a(1+tanh z)
}
static __device__ __forceinline__ float dot2(f16x2 a, f16x2 b, float c) {
#if __has_builtin(__builtin_amdgcn_fdot2)
  return __builtin_amdgcn_fdot2(a, b, c, false);
#else
  return c + (float)a[0] * (float)b[0] + (float)a[1] * (float)b[1];
#endif
}
template <typename T, typename F>
static __device__ __forceinline__ T bcast(F v) {
  union { F f; T t; } u; u.f = v; return u.t;
}
// f16 bits -> e5m2 byte (RNE truncation of top byte)
static __device__ __forceinline__ unsigned char f16_to_bf8(_Float16 h) {
  unsigned short b = bcast<unsigned short>(h);
  unsigned t = (unsigned)b + 0x7Fu + ((b >> 8) & 1u);
  return (unsigned char)(t >> 8);
}
// inline dtype detect: every wave samples the same 1024 words of x (identical
// result everywhere) -- replaces the k_detect launch + flag buffer.
static __device__ __forceinline__ int detect_isf(const unsigned* __restrict__ x) {
  const int lane = threadIdx.x & 63;
  int good = 0;
  #pragma unroll
  for (int i = 0; i < 16; ++i) {
    float v = fabsf(bf2f((unsigned short)(x[lane + i * 64] & 0xFFFFu)));
    good += (v >= 0.0009765625f && v <= 32.0f) ? 1 : 0;
  }
  #pragma unroll
  for (int o = 1; o < 64; o <<= 1) good += __shfl_xor(good, o);
  return (good < 512) ? 1 : 0;   // 1 => inputs are f32
}

// param-block element offsets (bf16 canonical)
#define PC_G1   0
#define PC_B1   128
#define PC_WQ   256
#define PC_BQ   16640
#define PC_WK   16768
#define PC_BK   33152
#define PC_WV   33280
#define PC_BV   49664
#define PC_EB   49792
#define PC_WO   49824
#define PC_BO   66208
#define PC_G2   66336
#define PC_B2   66464
#define PC_W1   66592
#define PC_B1F  99360
#define PC_W2   99616
#define PC_B2F  132384
#define PC_TOT  132512
#define B_CONV  518   // ceil(PC_TOT/256)

#define MAXBUCK 512
#define OFLCAP  8192

// ---------- fused: param prep (+weight repack) || binned edge scatter ----------
struct PP { const void* p[17]; };

static __device__ __forceinline__ unsigned short rdw(const void* p, int isf, int idx) {
  return isf ? f2bf(((const float*)p)[idx]) : ((const unsigned short*)p)[idx];
}
static __device__ __forceinline__ void pack_one(
    const void* w, int isf, int rs, int K, int ntl_n,
    unsigned short* __restrict__ dst, int nt0, int idx)
{
  int k32 = K >> 5;
  if (idx >= ntl_n * k32 * 64) return;
  int lane = idx & 63;
  int ks = (idx >> 6) % k32;
  int ntl = idx / (64 * k32);
  int m = lane & 15, q = lane >> 4;
  int col = ntl * 16 + m;
  int kb = ks * 32 + q * 8;
  unsigned short tmp[8];
  #pragma unroll
  for (int j = 0; j < 8; ++j) tmp[j] = rdw(w, isf, (kb + j) * rs + col);
  *(uint4*)&dst[(size_t)(((nt0 + ntl) * k32 + ks) * 64 + lane) * 8] = *(const uint4*)tmp;
}

// Blocks [0, B_CONV+66): param conversion + weight repack.
// Blocks [B_CONV+66, +bb): binned scatter of edges into fixed-capacity bucket
// regions of tmp (bucket b owns [b*CAP, (b+1)*CAP)); per-block LDS histogram +
// one global atomic per (block,bucket) reserves a contiguous run. Rare overflow
// (run past CAP) spills per-edge to ofl[] -- exactness for any input.
__global__ __launch_bounds__(256) void k_prep(
    PP pp, const unsigned* __restrict__ xdet, unsigned short* __restrict__ pc,
    unsigned short* __restrict__ wqkvp, unsigned short* __restrict__ wop,
    unsigned short* __restrict__ w1p, unsigned short* __restrict__ w2p,
    unsigned short* __restrict__ bqkvb,
    const int* __restrict__ ei, const int* __restrict__ et,
    int* __restrict__ bfill, unsigned* __restrict__ tmp,
    int2* __restrict__ ofl, int* __restrict__ ofl_cnt,
    int E, int nbuck, int shift, int CAP, int bb)
{
  __shared__ int cnt[MAXBUCK];
  const int b = blockIdx.x, tid = threadIdx.x;
  if (b < B_CONV + 66) {
    const int isf = detect_isf(xdet);
    if (b < B_CONV) {
      const int offs[18] = {PC_G1,PC_B1,PC_WQ,PC_BQ,PC_WK,PC_BK,PC_WV,PC_BV,PC_EB,
                            PC_WO,PC_BO,PC_G2,PC_B2,PC_W1,PC_B1F,PC_W2,PC_B2F,PC_TOT};
      int i = b * 256 + tid;
      if (i >= PC_TOT) return;
      int s = 0;
      while (i >= offs[s + 1]) ++s;
      pc[i] = rdw(pp.p[s], isf, i - offs[s]);
    } else if (b < B_CONV + 8)  pack_one(pp.p[2],  isf, 128, 128, 8,  wqkvp, 0,  (b - B_CONV) * 256 + tid);
    else if (b < B_CONV + 16)   pack_one(pp.p[4],  isf, 128, 128, 8,  wqkvp, 8,  (b - B_CONV - 8) * 256 + tid);
    else if (b < B_CONV + 24)   pack_one(pp.p[6],  isf, 128, 128, 8,  wqkvp, 16, (b - B_CONV - 16) * 256 + tid);
    else if (b < B_CONV + 32)   pack_one(pp.p[9],  isf, 128, 128, 8,  wop,   0,  (b - B_CONV - 24) * 256 + tid);
    else if (b < B_CONV + 48)   pack_one(pp.p[13], isf, 256, 128, 16, w1p,   0,  (b - B_CONV - 32) * 256 + tid);
    else if (b < B_CONV + 64)   pack_one(pp.p[15], isf, 128, 256, 8,  w2p,   0,  (b - B_CONV - 48) * 256 + tid);
    else {
      int i = (b - B_CONV - 64) * 256 + tid;
      if (i < 384) {
        int s = i >> 7, c = i & 127;
        const void* src = (s == 0) ? pp.p[3] : ((s == 1) ? pp.p[5] : pp.p[7]);
        bqkvb[i] = rdw(src, isf, c);
      }
    }
    return;
  }

  // ---- binned scatter ----
  const int bsb = b - (B_CONV + 66);
  const unsigned lowmask = (1u << shift) - 1u;
  for (int base = bsb * 4096; base < E; base += bb * 4096) {
    for (int i = tid; i < nbuck; i += 256) cnt[i] = 0;
    __syncthreads();
    unsigned pk[16]; int bk[16];
    #pragma unroll
    for (int u = 0; u < 16; ++u) {
      int e = base + u * 256 + tid;
      if (e < E) {
        unsigned s = (unsigned)ei[e];
        unsigned d = (unsigned)ei[E + e];
        unsigned t = (unsigned)et[e];
        int bq = min((int)(d >> shift), nbuck - 1);
        pk[u] = s | (t << 18) | ((d & lowmask) << 20);
        bk[u] = bq;
        atomicAdd(&cnt[bq], 1);
      } else bk[u] = -1;
    }
    __syncthreads();
    for (int i = tid; i < nbuck; i += 256) {
      int c = cnt[i];
      cnt[i] = c ? i * CAP + atomicAdd(&bfill[i], c) : 0;
    }
    __syncthreads();
    #pragma unroll
    for (int u = 0; u < 16; ++u) {
      if (bk[u] >= 0) {
        int pos = atomicAdd(&cnt[bk[u]], 1);
        if (pos < (bk[u] + 1) * CAP) {
          tmp[pos] = pk[u];
        } else {
          int oi = atomicAdd(ofl_cnt, 1);
          if (oi < OFLCAP) { int2 o; o.x = (int)pk[u]; o.y = bk[u]; ofl[oi] = o; }
        }
      }
    }
    __syncthreads();
  }
}

// ---------- fused: LN1+QKV GEMM || per-bucket CSR sort ----------
__global__ __launch_bounds__(256) void k_lnqkv(
    const void* __restrict__ xin,
    const unsigned short* __restrict__ pc,
    const unsigned short* __restrict__ bias,
    const unsigned short* __restrict__ wpack,
    _Float16* __restrict__ qb, unsigned char* __restrict__ kvb, int N, int NB,
    const unsigned* __restrict__ tmp, const int* __restrict__ bfill,
    const int2* __restrict__ ofl, const int* __restrict__ ofl_cnt,
    int* __restrict__ rowptr, unsigned* __restrict__ packed,
    int nbuck, int shift, int CAP)
{
  __shared__ __align__(16) char shraw[64 * 136 * 2];   // 17408 B arena
  const int tid = threadIdx.x, lane = tid & 63, wv = tid >> 6;

  if ((int)blockIdx.x >= NB) {
    // ---- bucketsort ----
    int* cnt = (int*)shraw;                  // 1024 ints
    int* cur = (int*)(shraw + 4096);         // 1024 ints
    int* ws  = (int*)(shraw + 8192);         // 4 ints
    int* rs  = (int*)(shraw + 8224);         // 8 ints
    int* carry_s = (int*)(shraw + 8256);
    const int bw = 1 << shift;
    const int b2 = (int)blockIdx.x - NB;
    const int n0 = b2 << shift;

    int s_before = 0, s_all = 0;
    for (int i = tid; i < nbuck; i += 256) {
      int v = bfill[i];
      s_all += v;
      if (i < b2) s_before += v;
    }
    #pragma unroll
    for (int o = 1; o < 64; o <<= 1) {
      s_before += __shfl_xor(s_before, o);
      s_all    += __shfl_xor(s_all, o);
    }
    if (lane == 0) { rs[wv] = s_before; rs[4 + wv] = s_all; }
    for (int i = tid; i < bw; i += 256) cnt[i] = 0;
    if (tid == 0) *carry_s = 0;
    __syncthreads();
    const int beg = rs[0] + rs[1] + rs[2] + rs[3];
    const int tot = rs[4] + rs[5] + rs[6] + rs[7];
    const int stored = min(bfill[b2], CAP);
    const int tbase = b2 * CAP;
    if (b2 == 0 && tid == 0) rowptr[N] = tot;
    const int onum = min(*ofl_cnt, OFLCAP);

    for (int i = tid; i < stored; i += 256)
      atomicAdd(&cnt[(tmp[tbase + i] >> 20) & (unsigned)(bw - 1)], 1);
    for (int i = tid; i < onum; i += 256) {
      int2 o = ofl[i];
      if (o.y == b2) atomicAdd(&cnt[(((unsigned)o.x) >> 20) & (unsigned)(bw - 1)], 1);
    }
    __syncthreads();
    for (int base = 0; base < bw; base += 256) {
      int i = base + tid;
      int v = (i < bw) ? cnt[i] : 0;
      int s = v;
      #pragma unroll
      for (int o = 1; o < 64; o <<= 1) { int t = __shfl_up(s, o); if (lane >= o) s += t; }
      if (lane == 63) ws[wv] = s;
      int c = *carry_s;
      __syncthreads();
      int off = c;
      for (int k = 0; k < wv; ++k) off += ws[k];
      if (i < bw) {
        int excl = beg + off + s - v;
        cur[i] = excl;
        if (n0 + i < N) rowptr[n0 + i] = excl;
      }
      __syncthreads();
      if (tid == 0) *carry_s = c + ws[0] + ws[1] + ws[2] + ws[3];
      __syncthreads();
    }
    for (int i = tid; i < stored; i += 256) {
      unsigned pk = tmp[tbase + i];
      int dl = (int)((pk >> 20) & (unsigned)(bw - 1));
      int pos = atomicAdd(&cur[dl], 1);
      packed[pos] = pk;   // dlow bits stay in 20+; attn masks type with &3
    }
    for (int i = tid; i < onum; i += 256) {
      int2 o = ofl[i];
      if (o.y == b2) {
        unsigned pk = (unsigned)o.x;
        int dl = (int)((pk >> 20) & (unsigned)(bw - 1));
        int pos = atomicAdd(&cur[dl], 1);
        packed[pos] = pk;
      }
    }
    return;
  }

  // ---- LN1 + QKV ----
  unsigned short* H = (unsigned short*)shraw;   // 64 x 136
  const int row0 = blockIdx.x * 64;
  const int isf = detect_isf((const unsigned*)xin);
  {
    const int rl = tid >> 2, c0 = (tid & 3) * 32;
    const int r = row0 + rl;
    float xv[32];
    if (r < N) {
      if (isf) {
        const float4* xp = (const float4*)((const float*)xin + (size_t)r * 128 + c0);
        #pragma unroll
        for (int u = 0; u < 8; ++u) {
          float4 f = xp[u];
          xv[u*4] = f.x; xv[u*4+1] = f.y; xv[u*4+2] = f.z; xv[u*4+3] = f.w;
        }
      } else {
        const uint4* xp = (const uint4*)((const unsigned short*)xin + (size_t)r * 128 + c0);
        #pragma unroll
        for (int u = 0; u < 4; ++u) {
          uint4 w = xp[u];
          unsigned ww[4] = {w.x, w.y, w.z, w.w};
          #pragma unroll
          for (int p = 0; p < 4; ++p) {
            xv[u*8 + 2*p]     = bf2f((unsigned short)ww[p]);
            xv[u*8 + 2*p + 1] = bf2f((unsigned short)(ww[p] >> 16));
          }
        }
      }
    } else {
      #pragma unroll
      for (int u = 0; u < 32; ++u) xv[u] = 0.f;
    }
    float s = 0.f, s2 = 0.f;
    #pragma unroll
    for (int u = 0; u < 32; ++u) { s += xv[u]; s2 += xv[u] * xv[u]; }
    s += __shfl_xor(s, 1); s2 += __shfl_xor(s2, 1);
    s += __shfl_xor(s, 2); s2 += __shfl_xor(s2, 2);
    float mean = s * (1.f / 128.f);
    float var  = fmaxf(s2 * (1.f / 128.f) - mean * mean, 0.f);
    float inv  = rsqrtf(var + 1e-5f);
    unsigned short hb[32];
    #pragma unroll
    for (int u = 0; u < 32; ++u) {
      int c = c0 + u;
      hb[u] = f2bf((xv[u] - mean) * inv * bf2f(pc[PC_G1 + c]) + bf2f(pc[PC_B1 + c]));
    }
    uint4* hp = (uint4*)&H[rl * 136 + c0];
    #pragma unroll
    for (int u = 0; u < 4; ++u) hp[u] = ((const uint4*)hb)[u];
  }
  __syncthreads();

  const int wave = wv;
  const int m = lane & 15, q = lane >> 4;
  bf16x8 a[16];
  #pragma unroll
  for (int rt = 0; rt < 4; ++rt) {
    const unsigned short* hrow = &H[(rt * 16 + m) * 136 + q * 8];
    #pragma unroll
    for (int ks = 0; ks < 4; ++ks) a[rt*4+ks] = *(const bf16x8*)&hrow[ks * 32];
  }
  const f32x4 z = {0.f, 0.f, 0.f, 0.f};
  #pragma unroll
  for (int p = 0; p < 3; ++p) {
    bf16x8 bfr[8];
    #pragma unroll
    for (int tt = 0; tt < 2; ++tt)
      #pragma unroll
      for (int ks = 0; ks < 4; ++ks)
        bfr[tt*4+ks] = *(const bf16x8*)&wpack[(size_t)(((wave*6 + 2*p + tt)*4 + ks)*64 + lane)*8];
    f32x4 c[4][2];
    #pragma unroll
    for (int rt = 0; rt < 4; ++rt) { c[rt][0] = z; c[rt][1] = z; }
    #pragma unroll
    for (int rt = 0; rt < 4; ++rt)
      #pragma unroll
      for (int ks = 0; ks < 4; ++ks) {
        c[rt][0] = __builtin_amdgcn_mfma_f32_16x16x32_bf16(a[rt*4+ks], bfr[ks],   c[rt][0], 0, 0, 0);
        c[rt][1] = __builtin_amdgcn_mfma_f32_16x16x32_bf16(a[rt*4+ks], bfr[4+ks], c[rt][1], 0, 0, 0);
      }
    #pragma unroll
    for (int tt = 0; tt < 2; ++tt) {
      int jj = (wave*6 + 2*p + tt) * 16 + m;
      float bv = bf2f(bias[jj]);
      #pragma unroll
      for (int rt = 0; rt < 4; ++rt)
        #pragma unroll
        for (int rr = 0; rr < 4; ++rr) {
          int row = row0 + rt*16 + q*4 + rr;
          if (row < N) {
            _Float16 hv = (_Float16)(c[rt][tt][rr] + bv);
            if (jj < 128) {
              qb[(size_t)row * 128 + jj] = hv;
            } else if (jj < 256) {
              int cc = jj - 128, h = cc >> 4, d = cc & 15;
              kvb[(size_t)row * 256 + h * 16 + d] = f16_to_bf8(hv);
            } else {
              int cc = jj - 256, h = cc >> 4, d = cc & 15;
              kvb[(size_t)row * 256 + 128 + h * 16 + d] = f16_to_bf8(hv);
            }
          }
        }
    }
  }
}

// ---------- attention: wave-per-node, lane=(edge,head), e5m2 KV, perm decode ----------
__global__ __launch_bounds__(256) void k_attn(
    const _Float16* __restrict__ qb, const unsigned char* __restrict__ kvb,
    const unsigned* __restrict__ packed, const int* __restrict__ rowptr,
    const unsigned short* __restrict__ pc, unsigned short* __restrict__ msgb,
    int N, int th)
{
  __shared__ float ebs[64];
  const int tid = threadIdx.x, lane = tid & 63, wave = tid >> 6;
  if (tid < th) ebs[tid] = bf2f(pc[PC_EB + tid]);
  __syncthreads();
  const int n = blockIdx.x * 4 + wave;
  if (n >= N) return;
  const int h = lane & 7, el = lane >> 3;

  f16x8 qa, qc;
  {
    const _Float16* qp = qb + (size_t)n * 128 + h * 16;
    qa = *(const f16x8*)qp;
    qc = *(const f16x8*)(qp + 8);
  }
  const int beg = rowptr[n], end = rowptr[n + 1];
  float l = 0.f;
  f16x8 accA = {0, 0, 0, 0, 0, 0, 0, 0};
  f16x8 accB = {0, 0, 0, 0, 0, 0, 0, 0};

  if (beg < end) {
    const int last = end - 1;
    unsigned pk = packed[min(beg + el, last)];
    const unsigned char* kp = kvb + (size_t)(pk & 0x3FFFF) * 256 + h * 16;
    uint4 kw = *(const uint4*)kp;
    uint4 vw = *(const uint4*)(kp + 128);

    for (int base = beg; base < end; base += 8) {
      unsigned pk2 = 0; uint4 kw2, vw2;
      const bool more = (base + 8) < end;   // wave-uniform
      if (more) {
        pk2 = packed[min(base + 8 + el, last)];
        const unsigned char* kp2 = kvb + (size_t)(pk2 & 0x3FFFF) * 256 + h * 16;
        kw2 = *(const uint4*)kp2;
        vw2 = *(const uint4*)(kp2 + 128);
      }

      // decode k (16 e5m2 bytes -> 8 f16x2 via v_perm) and dot with q
      float s = 0.f;
      {
        unsigned kd[4] = {kw.x, kw.y, kw.z, kw.w};
        #pragma unroll
        for (int j = 0; j < 2; ++j) {
          f16x2 klo = bcast<f16x2>(__builtin_amdgcn_perm(0u, kd[j], 0x010c000cu));
          f16x2 khi = bcast<f16x2>(__builtin_amdgcn_perm(0u, kd[j], 0x030c020cu));
          f16x2 a0 = {qa[4*j], qa[4*j+1]}, a1 = {qa[4*j+2], qa[4*j+3]};
          s = dot2(a0, klo, s);
          s = dot2(a1, khi, s);
        }
        #pragma unroll
        for (int j = 0; j < 2; ++j) {
          f16x2 klo = bcast<f16x2>(__builtin_amdgcn_perm(0u, kd[2+j], 0x010c000cu));
          f16x2 khi = bcast<f16x2>(__builtin_amdgcn_perm(0u, kd[2+j], 0x030c020cu));
          f16x2 a0 = {qc[4*j], qc[4*j+1]}, a1 = {qc[4*j+2], qc[4*j+3]};
          s = dot2(a0, klo, s);
          s = dot2(a1, khi, s);
        }
      }
      float sc = fminf(s * 0.25f + ebs[((pk >> 18) & 3u) * 8 + h], 80.f);
      float pe = (base + el < end) ? __expf(sc) : 0.f;
      l += pe;
      _Float16 pf = (_Float16)pe;
      f16x8 p8 = {pf, pf, pf, pf, pf, pf, pf, pf};
      // decode v and accumulate
      {
        unsigned vd[4] = {vw.x, vw.y, vw.z, vw.w};
        union { unsigned u[4]; f16x8 v; } va, vb;
        va.u[0] = __builtin_amdgcn_perm(0u, vd[0], 0x010c000cu);
        va.u[1] = __builtin_amdgcn_perm(0u, vd[0], 0x030c020cu);
        va.u[2] = __builtin_amdgcn_perm(0u, vd[1], 0x010c000cu);
        va.u[3] = __builtin_amdgcn_perm(0u, vd[1], 0x030c020cu);
        vb.u[0] = __builtin_amdgcn_perm(0u, vd[2], 0x010c000cu);
        vb.u[1] = __builtin_amdgcn_perm(0u, vd[2], 0x030c020cu);
        vb.u[2] = __builtin_amdgcn_perm(0u, vd[3], 0x010c000cu);
        vb.u[3] = __builtin_amdgcn_perm(0u, vd[3], 0x030c020cu);
        accA += p8 * va.v;
        accB += p8 * vb.v;
      }

      if (more) { pk = pk2; kw = kw2; vw = vw2; }
    }
  }

  #pragma unroll
  for (int mask = 8; mask <= 32; mask <<= 1) {
    l += __shfl_xor(l, mask);
    int2 ai = bcast<int2>(accA), bi = bcast<int2>(accB);
    int2 as, bs;
    as.x = __shfl_xor(ai.x, mask); as.y = __shfl_xor(ai.y, mask);
    bs.x = __shfl_xor(bi.x, mask); bs.y = __shfl_xor(bi.y, mask);
    accA += bcast<f16x8>(as);
    accB += bcast<f16x8>(bs);
  }
  if (el == 0) {
    float inv = 1.f / (l + 1e-9f);
    unsigned o[8];
    #pragma unroll
    for (int j = 0; j < 4; ++j)
      o[j] = packbf((float)accA[2*j] * inv, (float)accA[2*j+1] * inv);
    #pragma unroll
    for (int j = 0; j < 4; ++j)
      o[4+j] = packbf((float)accB[2*j] * inv, (float)accB[2*j+1] * inv);
    uint4* dst = (uint4*)(msgb + (size_t)n * 128 + h * 16);
    uint4 d0 = {o[0], o[1], o[2], o[3]}, d1 = {o[4], o[5], o[6], o[7]};
    dst[0] = d0; dst[1] = d1;
  }
}

// ---------- fused tail: 32-row blocks (25.6 KB LDS -> 6 blocks/CU) ----------
// msg@wo+res -> LN2 -> FFN1(gelu) -> FFN2+res -> out. Halving the row tile
// doubles resident blocks (3->6 per CU): 2x independent barrier-chains per CU
// to hide each phase's latency. Per-element arithmetic identical to 64-row
// version except LN2 reduce association (8 lanes x 16 vs 4 x 32).
__global__ __launch_bounds__(256) void k_tail(
    const void* __restrict__ xin,
    const unsigned short* __restrict__ msgb,
    const unsigned short* __restrict__ wop, const unsigned short* __restrict__ w1p,
    const unsigned short* __restrict__ w2p, const unsigned short* __restrict__ pc,
    void* __restrict__ out, int N)
{
  __shared__ unsigned short x1s[32 * 136];
  __shared__ unsigned short hts[32 * 264];   // LN2 phase: stride 136; FFN1-out: stride 264
  const int tid = threadIdx.x;
  const int row0 = blockIdx.x * 32;
  const int isf = detect_isf((const unsigned*)xin);
  const int wave = tid >> 6, lane = tid & 63;
  const int m = lane & 15, q = lane >> 4;
  const f32x4 z = {0.f, 0.f, 0.f, 0.f};

  bf16x8 b1[8];
  #pragma unroll
  for (int tt = 0; tt < 2; ++tt)
    #pragma unroll
    for (int ks = 0; ks < 4; ++ks)
      b1[tt*4+ks] = *(const bf16x8*)&wop[(size_t)(((2*wave + tt)*4 + ks)*64 + lane)*8];
  bf16x8 a1[8];
  #pragma unroll
  for (int rt = 0; rt < 2; ++rt) {
    const unsigned short* ap = msgb + (size_t)min(row0 + rt*16 + m, N - 1) * 128 + q * 8;
    #pragma unroll
    for (int ks = 0; ks < 4; ++ks) a1[rt*4+ks] = *(const bf16x8*)&ap[ks * 32];
  }

  // residual staging: 32 rows x 8 threads x 16 cols
  {
    int rl = tid >> 3, c0 = (tid & 7) * 16;
    int r = row0 + rl;
    unsigned short hb[16];
    if (r < N) {
      if (isf) {
        const float4* xp = (const float4*)((const float*)xin + (size_t)r * 128 + c0);
        #pragma unroll
        for (int u = 0; u < 4; ++u) {
          float4 f = xp[u];
          hb[u*4] = f2bf(f.x); hb[u*4+1] = f2bf(f.y);
          hb[u*4+2] = f2bf(f.z); hb[u*4+3] = f2bf(f.w);
        }
      } else {
        const uint4* xp = (const uint4*)((const unsigned short*)xin + (size_t)r * 128 + c0);
        #pragma unroll
        for (int u = 0; u < 2; ++u) ((uint4*)hb)[u] = xp[u];
      }
    } else {
      #pragma unroll
      for (int u = 0; u < 16; ++u) hb[u] = 0;
    }
    #pragma unroll
    for (int u = 0; u < 2; ++u) ((uint4*)&x1s[rl * 136 + c0])[u] = ((const uint4*)hb)[u];
  }
  __syncthreads();

  // GEMM1: attn_out @ wo (+bias +residual) -> x1s
  {
    f32x4 c[2][2];
    #pragma unroll
    for (int rt = 0; rt < 2; ++rt) { c[rt][0] = z; c[rt][1] = z; }
    #pragma unroll
    for (int rt = 0; rt < 2; ++rt)
      #pragma unroll
      for (int ks = 0; ks < 4; ++ks) {
        c[rt][0] = __builtin_amdgcn_mfma_f32_16x16x32_bf16(a1[rt*4+ks], b1[ks],   c[rt][0], 0, 0, 0);
        c[rt][1] = __builtin_amdgcn_mfma_f32_16x16x32_bf16(a1[rt*4+ks], b1[4+ks], c[rt][1], 0, 0, 0);
      }
    #pragma unroll
    for (int tt = 0; tt < 2; ++tt) {
      int col = (2*wave + tt) * 16 + m;
      float bv = bf2f(pc[PC_BO + col]);
      #pragma unroll
      for (int rt = 0; rt < 2; ++rt)
        #pragma unroll
        for (int rr = 0; rr < 4; ++rr) {
          int rl = rt*16 + q*4 + rr;
          float o = c[rt][tt][rr] + bv + bf2f(x1s[rl * 136 + col]);
          x1s[rl * 136 + col] = f2bf(o);
        }
    }
  }
  __syncthreads();

  bf16x8 b2[16];
  #pragma unroll
  for (int u = 0; u < 4; ++u)
    #pragma unroll
    for (int ks = 0; ks < 4; ++ks)
      b2[u*4+ks] = *(const bf16x8*)&w1p[(size_t)(((4*wave + u)*4 + ks)*64 + lane)*8];

  // LN2: 32 rows x 8 threads x 16 cols (reduce over 8 lanes)
  {
    int rl = tid >> 3, c0 = (tid & 7) * 16;
    unsigned short hb[16];
    #pragma unroll
    for (int u = 0; u < 2; ++u) ((uint4*)hb)[u] = *(const uint4*)&x1s[rl * 136 + c0 + u * 8];
    float xv[16];
    #pragma unroll
    for (int u = 0; u < 16; ++u) xv[u] = bf2f(hb[u]);
    float s = 0.f, s2 = 0.f;
    #pragma unroll
    for (int u = 0; u < 16; ++u) { s += xv[u]; s2 += xv[u] * xv[u]; }
    s += __shfl_xor(s, 1); s2 += __shfl_xor(s2, 1);
    s += __shfl_xor(s, 2); s2 += __shfl_xor(s2, 2);
    s += __shfl_xor(s, 4); s2 += __shfl_xor(s2, 4);
    float mean = s * (1.f / 128.f);
    float var  = fmaxf(s2 * (1.f / 128.f) - mean * mean, 0.f);
    float inv  = rsqrtf(var + 1e-5f);
    #pragma unroll
    for (int u = 0; u < 16; ++u) {
      int c = c0 + u;
      hb[u] = f2bf((xv[u] - mean) * inv * bf2f(pc[PC_G2 + c]) + bf2f(pc[PC_B2 + c]));
    }
    #pragma unroll
    for (int u = 0; u < 2; ++u) ((uint4*)&hts[rl * 136 + c0])[u] = ((const uint4*)hb)[u];
  }
  __syncthreads();

  bf16x8 a2[8];
  #pragma unroll
  for (int rt = 0; rt < 2; ++rt) {
    const unsigned short* hp = &hts[(rt*16 + m) * 136 + q * 8];
    #pragma unroll
    for (int ks = 0; ks < 4; ++ks) a2[rt*4+ks] = *(const bf16x8*)&hp[ks * 32];
  }
  __syncthreads();   // hts about to be reused (stride 264) as FFN1 output

  #pragma unroll
  for (int p = 0; p < 2; ++p) {
    f32x4 c[2][2];
    #pragma unroll
    for (int rt = 0; rt < 2; ++rt) { c[rt][0] = z; c[rt][1] = z; }
    #pragma unroll
    for (int rt = 0; rt < 2; ++rt)
      #pragma unroll
      for (int ks = 0; ks < 4; ++ks) {
        c[rt][0] = __builtin_amdgcn_mfma_f32_16x16x32_bf16(a2[rt*4+ks], b2[(2*p)*4+ks],   c[rt][0], 0, 0, 0);
        c[rt][1] = __builtin_amdgcn_mfma_f32_16x16x32_bf16(a2[rt*4+ks], b2[(2*p+1)*4+ks], c[rt][1], 0, 0, 0);
      }
    #pragma unroll
    for (int tt = 0; tt < 2; ++tt) {
      int col = (4*wave + 2*p + tt) * 16 + m;
      float bv = bf2f(pc[PC_B1F + col]);
      #pragma unroll
      for (int rt = 0; rt < 2; ++rt)
        #pragma unroll
        for (int rr = 0; rr < 4; ++rr)
          hts[(rt*16 + q*4 + rr) * 264 + col] = f2bf(gelu_fast(c[rt][tt][rr] + bv));
    }
  }

  bf16x8 b3[16];
  #pragma unroll
  for (int tt = 0; tt < 2; ++tt)
    #pragma unroll
    for (int ks = 0; ks < 8; ++ks)
      b3[tt*8+ks] = *(const bf16x8*)&w2p[(size_t)(((2*wave + tt)*8 + ks)*64 + lane)*8];
  __syncthreads();

  #pragma unroll
  for (int rt = 0; rt < 2; ++rt) {
    bf16x8 a3[8];
    const unsigned short* tp = &hts[(rt*16 + m) * 264 + q * 8];
    #pragma unroll
    for (int ks = 0; ks < 8; ++ks) a3[ks] = *(const bf16x8*)&tp[ks * 32];
    f32x4 c0 = z, c1 = z;
    #pragma unroll
    for (int ks = 0; ks < 8; ++ks) {
      c0 = __builtin_amdgcn_mfma_f32_16x16x32_bf16(a3[ks], b3[ks],   c0, 0, 0, 0);
      c1 = __builtin_amdgcn_mfma_f32_16x16x32_bf16(a3[ks], b3[8+ks], c1, 0, 0, 0);
    }
    #pragma unroll
    for (int tt = 0; tt < 2; ++tt) {
      f32x4 cc = tt ? c1 : c0;
      int col = (2*wave + tt) * 16 + m;
      float bv = bf2f(pc[PC_B2F + col]);
      #pragma unroll
      for (int rr = 0; rr < 4; ++rr) {
        int rl = rt*16 + q*4 + rr;
        int row = row0 + rl;
        if (row < N) {
          float o = cc[rr] + bv + bf2f(x1s[rl * 136 + col]);
          if (isf) ((float*)out)[(size_t)row * 128 + col] = o;
          else     ((unsigned short*)out)[(size_t)row * 128 + col] = f2bf(o);
        }
      }
    }
  }
}

// ---------- launch ----------
extern "C" void kernel_launch(void* const* d_in, const int* in_sizes, int n_in,
                              void* d_out, int out_size, void* d_ws, size_t ws_size,
                              hipStream_t stream)
{
  const void* x = d_in[0];
  const int* ei = (const int*)d_in[1];
  const int* et = (const int*)d_in[2];
  const int N = in_sizes[0] / 128;
  const int E = in_sizes[2];
  int th = in_sizes[13];
  if (th > 64) th = 64;

  int shift = 7;
  while ((((N + (1 << shift) - 1) >> shift) > MAXBUCK) && shift < 10) ++shift;
  const int nbuck = (N + (1 << shift) - 1) >> shift;
  const int CAP = ((2 * (E / nbuck) + 512) + 63) & ~63;   // >>10 sigma headroom

  char* ws = (char*)d_ws;
  size_t off = 0;
  auto alloc = [&](size_t bytes) -> void* {
    void* p = ws + off; off += (bytes + 255) & ~(size_t)255; return p;
  };
  unsigned short* pc = (unsigned short*)alloc((size_t)PC_TOT * 2);
  _Float16* qb  = (_Float16*)alloc((size_t)N * 128 * 2);
  unsigned char* kvb = (unsigned char*)alloc((size_t)N * 256);
  unsigned* packed = (unsigned*)alloc((size_t)E * 4);
  unsigned* tmp = (unsigned*)alloc((size_t)nbuck * CAP * 4);
  int2* ofl = (int2*)alloc((size_t)OFLCAP * 8);
  int* rowptr = (int*)alloc((size_t)(N + 1) * 4);
  unsigned short* msgb = (unsigned short*)alloc((size_t)N * 128 * 2);
  unsigned short* wqkvp = (unsigned short*)alloc((size_t)128 * 384 * 2);
  unsigned short* wop   = (unsigned short*)alloc((size_t)128 * 128 * 2);
  unsigned short* w1p   = (unsigned short*)alloc((size_t)128 * 256 * 2);
  unsigned short* w2p   = (unsigned short*)alloc((size_t)256 * 128 * 2);
  unsigned short* bqkvb = (unsigned short*)alloc(384 * 2);
  size_t zoff = off;
  int* bfill   = (int*)alloc((size_t)MAXBUCK * 4);
  int* ofl_cnt = (int*)alloc(4);
  hipMemsetAsync(ws + zoff, 0, off - zoff, stream);

  PP pp;
  for (int i = 0; i < 17; ++i) pp.p[i] = d_in[5 + i];

  const int NB = (N + 63) / 64;
  const int bb = (E + 4095) / 4096;

  // fused: param prep || binned edge scatter (isf computed inline per wave)
  k_prep<<<B_CONV + 66 + bb, 256, 0, stream>>>(
      pp, (const unsigned*)x, pc, wqkvp, wop, w1p, w2p, bqkvb,
      ei, et, bfill, tmp, ofl, ofl_cnt, E, nbuck, shift, CAP, bb);

  // fused: LN1+QKV || per-bucket CSR sort
  k_lnqkv<<<NB + nbuck, 256, 0, stream>>>(
      x, pc, bqkvb, wqkvp, qb, kvb, N, NB,
      tmp, bfill, ofl, ofl_cnt, rowptr, packed, nbuck, shift, CAP);

  // attention (high-occupancy, 512B LDS) -> msgb
  k_attn<<<(N + 3) / 4, 256, 0, stream>>>(qb, kvb, packed, rowptr, pc, msgb, N, th);

  // fused tail: 32-row blocks
  k_tail<<<(N + 31) / 32, 256, 0, stream>>>(x, msgb, wop, w1p, w2p, pc, d_out, N);
}

// Round 12
// 219.515 us; speedup vs baseline: 1.2336x; 1.0295x over previous
//
#include <hip/hip_runtime.h>
#include <hip/hip_bf16.h>

typedef short bf16x8 __attribute__((ext_vector_type(8)));
typedef float f32x4 __attribute__((ext_vector_type(4)));
typedef _Float16 f16x2 __attribute__((ext_vector_type(2)));
typedef _Float16 f16x8 __attribute__((ext_vector_type(8)));

// ---------- helpers ----------
static __device__ __forceinline__ float bf2f(unsigned short u) {
  return __uint_as_float(((unsigned)u) << 16);
}
static __device__ __forceinline__ unsigned short f2bf(float f) {
  unsigned u = __float_as_uint(f);
  u += 0x7fffu + ((u >> 16) & 1u);   // RNE
  return (unsigned short)(u >> 16);
}
static __device__ __forceinline__ unsigned packbf(float a, float b) {
  return (unsigned)f2bf(a) | ((unsigned)f2bf(b) << 16);
}
// tanh-gelu via hardware exp: tanh(z) = 1 - 2/(exp(2z)+1)
static __device__ __forceinline__ float gelu_fast(float a) {
  float u = a * (1.5957691216057308f + 0.07135481627f * a * a);  // 2z
  float e = __expf(u);
  float r = __builtin_amdgcn_rcpf(e + 1.f);
  return a - a * r;   // a*(1 - 1/(e+1)) = 0.5a(1+tanh z)
}
static __device__ __forceinline__ float dot2(f16x2 a, f16x2 b, float c) {
#if __has_builtin(__builtin_amdgcn_fdot2)
  return __builtin_amdgcn_fdot2(a, b, c, false);
#else
  return c + (float)a[0] * (float)b[0] + (float)a[1] * (float)b[1];
#endif
}
template <typename T, typename F>
static __device__ __forceinline__ T bcast(F v) {
  union { F f; T t; } u; u.f = v; return u.t;
}
// f16 bits -> e5m2 byte (RNE truncation of top byte)
static __device__ __forceinline__ unsigned char f16_to_bf8(_Float16 h) {
  unsigned short b = bcast<unsigned short>(h);
  unsigned t = (unsigned)b + 0x7Fu + ((b >> 8) & 1u);
  return (unsigned char)(t >> 8);
}
// inline dtype detect: every wave samples the same 1024 words of x (identical
// result everywhere) -- replaces the k_detect launch + flag buffer.
static __device__ __forceinline__ int detect_isf(const unsigned* __restrict__ x) {
  const int lane = threadIdx.x & 63;
  int good = 0;
  #pragma unroll
  for (int i = 0; i < 16; ++i) {
    float v = fabsf(bf2f((unsigned short)(x[lane + i * 64] & 0xFFFFu)));
    good += (v >= 0.0009765625f && v <= 32.0f) ? 1 : 0;
  }
  #pragma unroll
  for (int o = 1; o < 64; o <<= 1) good += __shfl_xor(good, o);
  return (good < 512) ? 1 : 0;   // 1 => inputs are f32
}

// param-block element offsets (bf16 canonical)
#define PC_G1   0
#define PC_B1   128
#define PC_WQ   256
#define PC_BQ   16640
#define PC_WK   16768
#define PC_BK   33152
#define PC_WV   33280
#define PC_BV   49664
#define PC_EB   49792
#define PC_WO   49824
#define PC_BO   66208
#define PC_G2   66336
#define PC_B2   66464
#define PC_W1   66592
#define PC_B1F  99360
#define PC_W2   99616
#define PC_B2F  132384
#define PC_TOT  132512
#define B_CONV  518   // ceil(PC_TOT/256)

#define MAXBUCK 512
#define OFLCAP  8192

// ---------- fused: param prep (+weight repack) || binned edge scatter ----------
struct PP { const void* p[17]; };

static __device__ __forceinline__ unsigned short rdw(const void* p, int isf, int idx) {
  return isf ? f2bf(((const float*)p)[idx]) : ((const unsigned short*)p)[idx];
}
static __device__ __forceinline__ void pack_one(
    const void* w, int isf, int rs, int K, int ntl_n,
    unsigned short* __restrict__ dst, int nt0, int idx)
{
  int k32 = K >> 5;
  if (idx >= ntl_n * k32 * 64) return;
  int lane = idx & 63;
  int ks = (idx >> 6) % k32;
  int ntl = idx / (64 * k32);
  int m = lane & 15, q = lane >> 4;
  int col = ntl * 16 + m;
  int kb = ks * 32 + q * 8;
  unsigned short tmp[8];
  #pragma unroll
  for (int j = 0; j < 8; ++j) tmp[j] = rdw(w, isf, (kb + j) * rs + col);
  *(uint4*)&dst[(size_t)(((nt0 + ntl) * k32 + ks) * 64 + lane) * 8] = *(const uint4*)tmp;
}

// Blocks [0, B_CONV+66): param conversion + weight repack.
// Blocks [B_CONV+66, +bb): binned scatter of edges into fixed-capacity bucket
// regions of tmp; per-block LDS histogram + one global atomic per
// (block,bucket) reserves a contiguous run. Rare overflow spills to ofl[].
__global__ __launch_bounds__(256) void k_prep(
    PP pp, const unsigned* __restrict__ xdet, unsigned short* __restrict__ pc,
    unsigned short* __restrict__ wqkvp, unsigned short* __restrict__ wop,
    unsigned short* __restrict__ w1p, unsigned short* __restrict__ w2p,
    unsigned short* __restrict__ bqkvb,
    const int* __restrict__ ei, const int* __restrict__ et,
    int* __restrict__ bfill, unsigned* __restrict__ tmp,
    int2* __restrict__ ofl, int* __restrict__ ofl_cnt,
    int E, int nbuck, int shift, int CAP, int bb)
{
  __shared__ int cnt[MAXBUCK];
  const int b = blockIdx.x, tid = threadIdx.x;
  if (b < B_CONV + 66) {
    const int isf = detect_isf(xdet);
    if (b < B_CONV) {
      const int offs[18] = {PC_G1,PC_B1,PC_WQ,PC_BQ,PC_WK,PC_BK,PC_WV,PC_BV,PC_EB,
                            PC_WO,PC_BO,PC_G2,PC_B2,PC_W1,PC_B1F,PC_W2,PC_B2F,PC_TOT};
      int i = b * 256 + tid;
      if (i >= PC_TOT) return;
      int s = 0;
      while (i >= offs[s + 1]) ++s;
      pc[i] = rdw(pp.p[s], isf, i - offs[s]);
    } else if (b < B_CONV + 8)  pack_one(pp.p[2],  isf, 128, 128, 8,  wqkvp, 0,  (b - B_CONV) * 256 + tid);
    else if (b < B_CONV + 16)   pack_one(pp.p[4],  isf, 128, 128, 8,  wqkvp, 8,  (b - B_CONV - 8) * 256 + tid);
    else if (b < B_CONV + 24)   pack_one(pp.p[6],  isf, 128, 128, 8,  wqkvp, 16, (b - B_CONV - 16) * 256 + tid);
    else if (b < B_CONV + 32)   pack_one(pp.p[9],  isf, 128, 128, 8,  wop,   0,  (b - B_CONV - 24) * 256 + tid);
    else if (b < B_CONV + 48)   pack_one(pp.p[13], isf, 256, 128, 16, w1p,   0,  (b - B_CONV - 32) * 256 + tid);
    else if (b < B_CONV + 64)   pack_one(pp.p[15], isf, 128, 256, 8,  w2p,   0,  (b - B_CONV - 48) * 256 + tid);
    else {
      int i = (b - B_CONV - 64) * 256 + tid;
      if (i < 384) {
        int s = i >> 7, c = i & 127;
        const void* src = (s == 0) ? pp.p[3] : ((s == 1) ? pp.p[5] : pp.p[7]);
        bqkvb[i] = rdw(src, isf, c);
      }
    }
    return;
  }

  // ---- binned scatter ----
  const int bsb = b - (B_CONV + 66);
  const unsigned lowmask = (1u << shift) - 1u;
  for (int base = bsb * 4096; base < E; base += bb * 4096) {
    for (int i = tid; i < nbuck; i += 256) cnt[i] = 0;
    __syncthreads();
    unsigned pk[16]; int bk[16];
    #pragma unroll
    for (int u = 0; u < 16; ++u) {
      int e = base + u * 256 + tid;
      if (e < E) {
        unsigned s = (unsigned)ei[e];
        unsigned d = (unsigned)ei[E + e];
        unsigned t = (unsigned)et[e];
        int bq = min((int)(d >> shift), nbuck - 1);
        pk[u] = s | (t << 18) | ((d & lowmask) << 20);
        bk[u] = bq;
        atomicAdd(&cnt[bq], 1);
      } else bk[u] = -1;
    }
    __syncthreads();
    for (int i = tid; i < nbuck; i += 256) {
      int c = cnt[i];
      cnt[i] = c ? i * CAP + atomicAdd(&bfill[i], c) : 0;
    }
    __syncthreads();
    #pragma unroll
    for (int u = 0; u < 16; ++u) {
      if (bk[u] >= 0) {
        int pos = atomicAdd(&cnt[bk[u]], 1);
        if (pos < (bk[u] + 1) * CAP) {
          tmp[pos] = pk[u];
        } else {
          int oi = atomicAdd(ofl_cnt, 1);
          if (oi < OFLCAP) { int2 o; o.x = (int)pk[u]; o.y = bk[u]; ofl[oi] = o; }
        }
      }
    }
    __syncthreads();
  }
}

// ---------- fused: LN1+QKV GEMM (32-row blocks) || per-bucket CSR sort ----------
// Blocks [0, NB): 32 rows each; each wave owns 6 col-tiles for ALL 32 rows.
// LDS 8704 B (vs 17408 at 64-row) -> ~2x resident blocks/CU; VGPR drops with
// halved A-frag/accumulator live set. Same latency-hiding trade verified on
// k_tail in the previous round.
// Blocks [NB, NB+nbuck): per-bucket CSR sort (unchanged; arena fits in 8704 B).
__global__ __launch_bounds__(256) void k_lnqkv(
    const void* __restrict__ xin,
    const unsigned short* __restrict__ pc,
    const unsigned short* __restrict__ bias,
    const unsigned short* __restrict__ wpack,
    _Float16* __restrict__ qb, unsigned char* __restrict__ kvb, int N, int NB,
    const unsigned* __restrict__ tmp, const int* __restrict__ bfill,
    const int2* __restrict__ ofl, const int* __restrict__ ofl_cnt,
    int* __restrict__ rowptr, unsigned* __restrict__ packed,
    int nbuck, int shift, int CAP)
{
  __shared__ __align__(16) char shraw[32 * 136 * 2];   // 8704 B arena
  const int tid = threadIdx.x, lane = tid & 63, wv = tid >> 6;

  if ((int)blockIdx.x >= NB) {
    // ---- bucketsort (arena: 4096 + 4096 + 16 + 32 + 4 = 8260 B <= 8704) ----
    int* cnt = (int*)shraw;                  // 1024 ints
    int* cur = (int*)(shraw + 4096);         // 1024 ints
    int* ws  = (int*)(shraw + 8192);         // 4 ints
    int* rs  = (int*)(shraw + 8224);         // 8 ints
    int* carry_s = (int*)(shraw + 8256);
    const int bw = 1 << shift;
    const int b2 = (int)blockIdx.x - NB;
    const int n0 = b2 << shift;

    int s_before = 0, s_all = 0;
    for (int i = tid; i < nbuck; i += 256) {
      int v = bfill[i];
      s_all += v;
      if (i < b2) s_before += v;
    }
    #pragma unroll
    for (int o = 1; o < 64; o <<= 1) {
      s_before += __shfl_xor(s_before, o);
      s_all    += __shfl_xor(s_all, o);
    }
    if (lane == 0) { rs[wv] = s_before; rs[4 + wv] = s_all; }
    for (int i = tid; i < bw; i += 256) cnt[i] = 0;
    if (tid == 0) *carry_s = 0;
    __syncthreads();
    const int beg = rs[0] + rs[1] + rs[2] + rs[3];
    const int tot = rs[4] + rs[5] + rs[6] + rs[7];
    const int stored = min(bfill[b2], CAP);
    const int tbase = b2 * CAP;
    if (b2 == 0 && tid == 0) rowptr[N] = tot;
    const int onum = min(*ofl_cnt, OFLCAP);

    for (int i = tid; i < stored; i += 256)
      atomicAdd(&cnt[(tmp[tbase + i] >> 20) & (unsigned)(bw - 1)], 1);
    for (int i = tid; i < onum; i += 256) {
      int2 o = ofl[i];
      if (o.y == b2) atomicAdd(&cnt[(((unsigned)o.x) >> 20) & (unsigned)(bw - 1)], 1);
    }
    __syncthreads();
    for (int base = 0; base < bw; base += 256) {
      int i = base + tid;
      int v = (i < bw) ? cnt[i] : 0;
      int s = v;
      #pragma unroll
      for (int o = 1; o < 64; o <<= 1) { int t = __shfl_up(s, o); if (lane >= o) s += t; }
      if (lane == 63) ws[wv] = s;
      int c = *carry_s;
      __syncthreads();
      int off = c;
      for (int k = 0; k < wv; ++k) off += ws[k];
      if (i < bw) {
        int excl = beg + off + s - v;
        cur[i] = excl;
        if (n0 + i < N) rowptr[n0 + i] = excl;
      }
      __syncthreads();
      if (tid == 0) *carry_s = c + ws[0] + ws[1] + ws[2] + ws[3];
      __syncthreads();
    }
    for (int i = tid; i < stored; i += 256) {
      unsigned pk = tmp[tbase + i];
      int dl = (int)((pk >> 20) & (unsigned)(bw - 1));
      int pos = atomicAdd(&cur[dl], 1);
      packed[pos] = pk;   // dlow bits stay in 20+; attn masks type with &3
    }
    for (int i = tid; i < onum; i += 256) {
      int2 o = ofl[i];
      if (o.y == b2) {
        unsigned pk = (unsigned)o.x;
        int dl = (int)((pk >> 20) & (unsigned)(bw - 1));
        int pos = atomicAdd(&cur[dl], 1);
        packed[pos] = pk;
      }
    }
    return;
  }

  // ---- LN1 + QKV, 32 rows ----
  unsigned short* H = (unsigned short*)shraw;   // 32 x 136
  const int row0 = blockIdx.x * 32;
  const int isf = detect_isf((const unsigned*)xin);
  {
    const int rl = tid >> 3, c0 = (tid & 7) * 16;
    const int r = row0 + rl;
    float xv[16];
    if (r < N) {
      if (isf) {
        const float4* xp = (const float4*)((const float*)xin + (size_t)r * 128 + c0);
        #pragma unroll
        for (int u = 0; u < 4; ++u) {
          float4 f = xp[u];
          xv[u*4] = f.x; xv[u*4+1] = f.y; xv[u*4+2] = f.z; xv[u*4+3] = f.w;
        }
      } else {
        const uint4* xp = (const uint4*)((const unsigned short*)xin + (size_t)r * 128 + c0);
        #pragma unroll
        for (int u = 0; u < 2; ++u) {
          uint4 w = xp[u];
          unsigned ww[4] = {w.x, w.y, w.z, w.w};
          #pragma unroll
          for (int p = 0; p < 4; ++p) {
            xv[u*8 + 2*p]     = bf2f((unsigned short)ww[p]);
            xv[u*8 + 2*p + 1] = bf2f((unsigned short)(ww[p] >> 16));
          }
        }
      }
    } else {
      #pragma unroll
      for (int u = 0; u < 16; ++u) xv[u] = 0.f;
    }
    float s = 0.f, s2 = 0.f;
    #pragma unroll
    for (int u = 0; u < 16; ++u) { s += xv[u]; s2 += xv[u] * xv[u]; }
    s += __shfl_xor(s, 1); s2 += __shfl_xor(s2, 1);
    s += __shfl_xor(s, 2); s2 += __shfl_xor(s2, 2);
    s += __shfl_xor(s, 4); s2 += __shfl_xor(s2, 4);
    float mean = s * (1.f / 128.f);
    float var  = fmaxf(s2 * (1.f / 128.f) - mean * mean, 0.f);
    float inv  = rsqrtf(var + 1e-5f);
    unsigned short hb[16];
    #pragma unroll
    for (int u = 0; u < 16; ++u) {
      int c = c0 + u;
      hb[u] = f2bf((xv[u] - mean) * inv * bf2f(pc[PC_G1 + c]) + bf2f(pc[PC_B1 + c]));
    }
    uint4* hp = (uint4*)&H[rl * 136 + c0];
    #pragma unroll
    for (int u = 0; u < 2; ++u) hp[u] = ((const uint4*)hb)[u];
  }
  __syncthreads();

  const int wave = wv;
  const int m = lane & 15, q = lane >> 4;
  bf16x8 a[8];
  #pragma unroll
  for (int rt = 0; rt < 2; ++rt) {
    const unsigned short* hrow = &H[(rt * 16 + m) * 136 + q * 8];
    #pragma unroll
    for (int ks = 0; ks < 4; ++ks) a[rt*4+ks] = *(const bf16x8*)&hrow[ks * 32];
  }
  const f32x4 z = {0.f, 0.f, 0.f, 0.f};
  #pragma unroll
  for (int p = 0; p < 3; ++p) {
    bf16x8 bfr[8];
    #pragma unroll
    for (int tt = 0; tt < 2; ++tt)
      #pragma unroll
      for (int ks = 0; ks < 4; ++ks)
        bfr[tt*4+ks] = *(const bf16x8*)&wpack[(size_t)(((wave*6 + 2*p + tt)*4 + ks)*64 + lane)*8];
    f32x4 c[2][2];
    #pragma unroll
    for (int rt = 0; rt < 2; ++rt) { c[rt][0] = z; c[rt][1] = z; }
    #pragma unroll
    for (int rt = 0; rt < 2; ++rt)
      #pragma unroll
      for (int ks = 0; ks < 4; ++ks) {
        c[rt][0] = __builtin_amdgcn_mfma_f32_16x16x32_bf16(a[rt*4+ks], bfr[ks],   c[rt][0], 0, 0, 0);
        c[rt][1] = __builtin_amdgcn_mfma_f32_16x16x32_bf16(a[rt*4+ks], bfr[4+ks], c[rt][1], 0, 0, 0);
      }
    #pragma unroll
    for (int tt = 0; tt < 2; ++tt) {
      int jj = (wave*6 + 2*p + tt) * 16 + m;
      float bv = bf2f(bias[jj]);
      #pragma unroll
      for (int rt = 0; rt < 2; ++rt)
        #pragma unroll
        for (int rr = 0; rr < 4; ++rr) {
          int row = row0 + rt*16 + q*4 + rr;
          if (row < N) {
            _Float16 hv = (_Float16)(c[rt][tt][rr] + bv);
            if (jj < 128) {
              qb[(size_t)row * 128 + jj] = hv;
            } else if (jj < 256) {
              int cc = jj - 128, h = cc >> 4, d = cc & 15;
              kvb[(size_t)row * 256 + h * 16 + d] = f16_to_bf8(hv);
            } else {
              int cc = jj - 256, h = cc >> 4, d = cc & 15;
              kvb[(size_t)row * 256 + 128 + h * 16 + d] = f16_to_bf8(hv);
            }
          }
        }
    }
  }
}

// ---------- attention: wave-per-node, lane=(edge,head), e5m2 KV, perm decode ----------
__global__ __launch_bounds__(256) void k_attn(
    const _Float16* __restrict__ qb, const unsigned char* __restrict__ kvb,
    const unsigned* __restrict__ packed, const int* __restrict__ rowptr,
    const unsigned short* __restrict__ pc, unsigned short* __restrict__ msgb,
    int N, int th)
{
  __shared__ float ebs[64];
  const int tid = threadIdx.x, lane = tid & 63, wave = tid >> 6;
  if (tid < th) ebs[tid] = bf2f(pc[PC_EB + tid]);
  __syncthreads();
  const int n = blockIdx.x * 4 + wave;
  if (n >= N) return;
  const int h = lane & 7, el = lane >> 3;

  f16x8 qa, qc;
  {
    const _Float16* qp = qb + (size_t)n * 128 + h * 16;
    qa = *(const f16x8*)qp;
    qc = *(const f16x8*)(qp + 8);
  }
  const int beg = rowptr[n], end = rowptr[n + 1];
  float l = 0.f;
  f16x8 accA = {0, 0, 0, 0, 0, 0, 0, 0};
  f16x8 accB = {0, 0, 0, 0, 0, 0, 0, 0};

  if (beg < end) {
    const int last = end - 1;
    unsigned pk = packed[min(beg + el, last)];
    const unsigned char* kp = kvb + (size_t)(pk & 0x3FFFF) * 256 + h * 16;
    uint4 kw = *(const uint4*)kp;
    uint4 vw = *(const uint4*)(kp + 128);

    for (int base = beg; base < end; base += 8) {
      unsigned pk2 = 0; uint4 kw2, vw2;
      const bool more = (base + 8) < end;   // wave-uniform
      if (more) {
        pk2 = packed[min(base + 8 + el, last)];
        const unsigned char* kp2 = kvb + (size_t)(pk2 & 0x3FFFF) * 256 + h * 16;
        kw2 = *(const uint4*)kp2;
        vw2 = *(const uint4*)(kp2 + 128);
      }

      // decode k (16 e5m2 bytes -> 8 f16x2 via v_perm) and dot with q
      float s = 0.f;
      {
        unsigned kd[4] = {kw.x, kw.y, kw.z, kw.w};
        #pragma unroll
        for (int j = 0; j < 2; ++j) {
          f16x2 klo = bcast<f16x2>(__builtin_amdgcn_perm(0u, kd[j], 0x010c000cu));
          f16x2 khi = bcast<f16x2>(__builtin_amdgcn_perm(0u, kd[j], 0x030c020cu));
          f16x2 a0 = {qa[4*j], qa[4*j+1]}, a1 = {qa[4*j+2], qa[4*j+3]};
          s = dot2(a0, klo, s);
          s = dot2(a1, khi, s);
        }
        #pragma unroll
        for (int j = 0; j < 2; ++j) {
          f16x2 klo = bcast<f16x2>(__builtin_amdgcn_perm(0u, kd[2+j], 0x010c000cu));
          f16x2 khi = bcast<f16x2>(__builtin_amdgcn_perm(0u, kd[2+j], 0x030c020cu));
          f16x2 a0 = {qc[4*j], qc[4*j+1]}, a1 = {qc[4*j+2], qc[4*j+3]};
          s = dot2(a0, klo, s);
          s = dot2(a1, khi, s);
        }
      }
      float sc = fminf(s * 0.25f + ebs[((pk >> 18) & 3u) * 8 + h], 80.f);
      float pe = (base + el < end) ? __expf(sc) : 0.f;
      l += pe;
      _Float16 pf = (_Float16)pe;
      f16x8 p8 = {pf, pf, pf, pf, pf, pf, pf, pf};
      // decode v and accumulate
      {
        unsigned vd[4] = {vw.x, vw.y, vw.z, vw.w};
        union { unsigned u[4]; f16x8 v; } va, vb;
        va.u[0] = __builtin_amdgcn_perm(0u, vd[0], 0x010c000cu);
        va.u[1] = __builtin_amdgcn_perm(0u, vd[0], 0x030c020cu);
        va.u[2] = __builtin_amdgcn_perm(0u, vd[1], 0x010c000cu);
        va.u[3] = __builtin_amdgcn_perm(0u, vd[1], 0x030c020cu);
        vb.u[0] = __builtin_amdgcn_perm(0u, vd[2], 0x010c000cu);
        vb.u[1] = __builtin_amdgcn_perm(0u, vd[2], 0x030c020cu);
        vb.u[2] = __builtin_amdgcn_perm(0u, vd[3], 0x010c000cu);
        vb.u[3] = __builtin_amdgcn_perm(0u, vd[3], 0x030c020cu);
        accA += p8 * va.v;
        accB += p8 * vb.v;
      }

      if (more) { pk = pk2; kw = kw2; vw = vw2; }
    }
  }

  #pragma unroll
  for (int mask = 8; mask <= 32; mask <<= 1) {
    l += __shfl_xor(l, mask);
    int2 ai = bcast<int2>(accA), bi = bcast<int2>(accB);
    int2 as, bs;
    as.x = __shfl_xor(ai.x, mask); as.y = __shfl_xor(ai.y, mask);
    bs.x = __shfl_xor(bi.x, mask); bs.y = __shfl_xor(bi.y, mask);
    accA += bcast<f16x8>(as);
    accB += bcast<f16x8>(bs);
  }
  if (el == 0) {
    float inv = 1.f / (l + 1e-9f);
    unsigned o[8];
    #pragma unroll
    for (int j = 0; j < 4; ++j)
      o[j] = packbf((float)accA[2*j] * inv, (float)accA[2*j+1] * inv);
    #pragma unroll
    for (int j = 0; j < 4; ++j)
      o[4+j] = packbf((float)accB[2*j] * inv, (float)accB[2*j+1] * inv);
    uint4* dst = (uint4*)(msgb + (size_t)n * 128 + h * 16);
    uint4 d0 = {o[0], o[1], o[2], o[3]}, d1 = {o[4], o[5], o[6], o[7]};
    dst[0] = d0; dst[1] = d1;
  }
}

// ---------- fused tail: 32-row blocks (25.6 KB LDS -> 6 blocks/CU) ----------
__global__ __launch_bounds__(256) void k_tail(
    const void* __restrict__ xin,
    const unsigned short* __restrict__ msgb,
    const unsigned short* __restrict__ wop, const unsigned short* __restrict__ w1p,
    const unsigned short* __restrict__ w2p, const unsigned short* __restrict__ pc,
    void* __restrict__ out, int N)
{
  __shared__ unsigned short x1s[32 * 136];
  __shared__ unsigned short hts[32 * 264];   // LN2 phase: stride 136; FFN1-out: stride 264
  const int tid = threadIdx.x;
  const int row0 = blockIdx.x * 32;
  const int isf = detect_isf((const unsigned*)xin);
  const int wave = tid >> 6, lane = tid & 63;
  const int m = lane & 15, q = lane >> 4;
  const f32x4 z = {0.f, 0.f, 0.f, 0.f};

  bf16x8 b1[8];
  #pragma unroll
  for (int tt = 0; tt < 2; ++tt)
    #pragma unroll
    for (int ks = 0; ks < 4; ++ks)
      b1[tt*4+ks] = *(const bf16x8*)&wop[(size_t)(((2*wave + tt)*4 + ks)*64 + lane)*8];
  bf16x8 a1[8];
  #pragma unroll
  for (int rt = 0; rt < 2; ++rt) {
    const unsigned short* ap = msgb + (size_t)min(row0 + rt*16 + m, N - 1) * 128 + q * 8;
    #pragma unroll
    for (int ks = 0; ks < 4; ++ks) a1[rt*4+ks] = *(const bf16x8*)&ap[ks * 32];
  }

  // residual staging: 32 rows x 8 threads x 16 cols
  {
    int rl = tid >> 3, c0 = (tid & 7) * 16;
    int r = row0 + rl;
    unsigned short hb[16];
    if (r < N) {
      if (isf) {
        const float4* xp = (const float4*)((const float*)xin + (size_t)r * 128 + c0);
        #pragma unroll
        for (int u = 0; u < 4; ++u) {
          float4 f = xp[u];
          hb[u*4] = f2bf(f.x); hb[u*4+1] = f2bf(f.y);
          hb[u*4+2] = f2bf(f.z); hb[u*4+3] = f2bf(f.w);
        }
      } else {
        const uint4* xp = (const uint4*)((const unsigned short*)xin + (size_t)r * 128 + c0);
        #pragma unroll
        for (int u = 0; u < 2; ++u) ((uint4*)hb)[u] = xp[u];
      }
    } else {
      #pragma unroll
      for (int u = 0; u < 16; ++u) hb[u] = 0;
    }
    #pragma unroll
    for (int u = 0; u < 2; ++u) ((uint4*)&x1s[rl * 136 + c0])[u] = ((const uint4*)hb)[u];
  }
  __syncthreads();

  // GEMM1: attn_out @ wo (+bias +residual) -> x1s
  {
    f32x4 c[2][2];
    #pragma unroll
    for (int rt = 0; rt < 2; ++rt) { c[rt][0] = z; c[rt][1] = z; }
    #pragma unroll
    for (int rt = 0; rt < 2; ++rt)
      #pragma unroll
      for (int ks = 0; ks < 4; ++ks) {
        c[rt][0] = __builtin_amdgcn_mfma_f32_16x16x32_bf16(a1[rt*4+ks], b1[ks],   c[rt][0], 0, 0, 0);
        c[rt][1] = __builtin_amdgcn_mfma_f32_16x16x32_bf16(a1[rt*4+ks], b1[4+ks], c[rt][1], 0, 0, 0);
      }
    #pragma unroll
    for (int tt = 0; tt < 2; ++tt) {
      int col = (2*wave + tt) * 16 + m;
      float bv = bf2f(pc[PC_BO + col]);
      #pragma unroll
      for (int rt = 0; rt < 2; ++rt)
        #pragma unroll
        for (int rr = 0; rr < 4; ++rr) {
          int rl = rt*16 + q*4 + rr;
          float o = c[rt][tt][rr] + bv + bf2f(x1s[rl * 136 + col]);
          x1s[rl * 136 + col] = f2bf(o);
        }
    }
  }
  __syncthreads();

  bf16x8 b2[16];
  #pragma unroll
  for (int u = 0; u < 4; ++u)
    #pragma unroll
    for (int ks = 0; ks < 4; ++ks)
      b2[u*4+ks] = *(const bf16x8*)&w1p[(size_t)(((4*wave + u)*4 + ks)*64 + lane)*8];

  // LN2: 32 rows x 8 threads x 16 cols (reduce over 8 lanes)
  {
    int rl = tid >> 3, c0 = (tid & 7) * 16;
    unsigned short hb[16];
    #pragma unroll
    for (int u = 0; u < 2; ++u) ((uint4*)hb)[u] = *(const uint4*)&x1s[rl * 136 + c0 + u * 8];
    float xv[16];
    #pragma unroll
    for (int u = 0; u < 16; ++u) xv[u] = bf2f(hb[u]);
    float s = 0.f, s2 = 0.f;
    #pragma unroll
    for (int u = 0; u < 16; ++u) { s += xv[u]; s2 += xv[u] * xv[u]; }
    s += __shfl_xor(s, 1); s2 += __shfl_xor(s2, 1);
    s += __shfl_xor(s, 2); s2 += __shfl_xor(s2, 2);
    s += __shfl_xor(s, 4); s2 += __shfl_xor(s2, 4);
    float mean = s * (1.f / 128.f);
    float var  = fmaxf(s2 * (1.f / 128.f) - mean * mean, 0.f);
    float inv  = rsqrtf(var + 1e-5f);
    #pragma unroll
    for (int u = 0; u < 16; ++u) {
      int c = c0 + u;
      hb[u] = f2bf((xv[u] - mean) * inv * bf2f(pc[PC_G2 + c]) + bf2f(pc[PC_B2 + c]));
    }
    #pragma unroll
    for (int u = 0; u < 2; ++u) ((uint4*)&hts[rl * 136 + c0])[u] = ((const uint4*)hb)[u];
  }
  __syncthreads();

  bf16x8 a2[8];
  #pragma unroll
  for (int rt = 0; rt < 2; ++rt) {
    const unsigned short* hp = &hts[(rt*16 + m) * 136 + q * 8];
    #pragma unroll
    for (int ks = 0; ks < 4; ++ks) a2[rt*4+ks] = *(const bf16x8*)&hp[ks * 32];
  }
  __syncthreads();   // hts about to be reused (stride 264) as FFN1 output

  #pragma unroll
  for (int p = 0; p < 2; ++p) {
    f32x4 c[2][2];
    #pragma unroll
    for (int rt = 0; rt < 2; ++rt) { c[rt][0] = z; c[rt][1] = z; }
    #pragma unroll
    for (int rt = 0; rt < 2; ++rt)
      #pragma unroll
      for (int ks = 0; ks < 4; ++ks) {
        c[rt][0] = __builtin_amdgcn_mfma_f32_16x16x32_bf16(a2[rt*4+ks], b2[(2*p)*4+ks],   c[rt][0], 0, 0, 0);
        c[rt][1] = __builtin_amdgcn_mfma_f32_16x16x32_bf16(a2[rt*4+ks], b2[(2*p+1)*4+ks], c[rt][1], 0, 0, 0);
      }
    #pragma unroll
    for (int tt = 0; tt < 2; ++tt) {
      int col = (4*wave + 2*p + tt) * 16 + m;
      float bv = bf2f(pc[PC_B1F + col]);
      #pragma unroll
      for (int rt = 0; rt < 2; ++rt)
        #pragma unroll
        for (int rr = 0; rr < 4; ++rr)
          hts[(rt*16 + q*4 + rr) * 264 + col] = f2bf(gelu_fast(c[rt][tt][rr] + bv));
    }
  }

  bf16x8 b3[16];
  #pragma unroll
  for (int tt = 0; tt < 2; ++tt)
    #pragma unroll
    for (int ks = 0; ks < 8; ++ks)
      b3[tt*8+ks] = *(const bf16x8*)&w2p[(size_t)(((2*wave + tt)*8 + ks)*64 + lane)*8];
  __syncthreads();

  #pragma unroll
  for (int rt = 0; rt < 2; ++rt) {
    bf16x8 a3[8];
    const unsigned short* tp = &hts[(rt*16 + m) * 264 + q * 8];
    #pragma unroll
    for (int ks = 0; ks < 8; ++ks) a3[ks] = *(const bf16x8*)&tp[ks * 32];
    f32x4 c0 = z, c1 = z;
    #pragma unroll
    for (int ks = 0; ks < 8; ++ks) {
      c0 = __builtin_amdgcn_mfma_f32_16x16x32_bf16(a3[ks], b3[ks],   c0, 0, 0, 0);
      c1 = __builtin_amdgcn_mfma_f32_16x16x32_bf16(a3[ks], b3[8+ks], c1, 0, 0, 0);
    }
    #pragma unroll
    for (int tt = 0; tt < 2; ++tt) {
      f32x4 cc = tt ? c1 : c0;
      int col = (2*wave + tt) * 16 + m;
      float bv = bf2f(pc[PC_B2F + col]);
      #pragma unroll
      for (int rr = 0; rr < 4; ++rr) {
        int rl = rt*16 + q*4 + rr;
        int row = row0 + rl;
        if (row < N) {
          float o = cc[rr] + bv + bf2f(x1s[rl * 136 + col]);
          if (isf) ((float*)out)[(size_t)row * 128 + col] = o;
          else     ((unsigned short*)out)[(size_t)row * 128 + col] = f2bf(o);
        }
      }
    }
  }
}

// ---------- launch ----------
extern "C" void kernel_launch(void* const* d_in, const int* in_sizes, int n_in,
                              void* d_out, int out_size, void* d_ws, size_t ws_size,
                              hipStream_t stream)
{
  const void* x = d_in[0];
  const int* ei = (const int*)d_in[1];
  const int* et = (const int*)d_in[2];
  const int N = in_sizes[0] / 128;
  const int E = in_sizes[2];
  int th = in_sizes[13];
  if (th > 64) th = 64;

  int shift = 7;
  while ((((N + (1 << shift) - 1) >> shift) > MAXBUCK) && shift < 10) ++shift;
  const int nbuck = (N + (1 << shift) - 1) >> shift;
  const int CAP = ((2 * (E / nbuck) + 512) + 63) & ~63;   // >>10 sigma headroom

  char* ws = (char*)d_ws;
  size_t off = 0;
  auto alloc = [&](size_t bytes) -> void* {
    void* p = ws + off; off += (bytes + 255) & ~(size_t)255; return p;
  };
  unsigned short* pc = (unsigned short*)alloc((size_t)PC_TOT * 2);
  _Float16* qb  = (_Float16*)alloc((size_t)N * 128 * 2);
  unsigned char* kvb = (unsigned char*)alloc((size_t)N * 256);
  unsigned* packed = (unsigned*)alloc((size_t)E * 4);
  unsigned* tmp = (unsigned*)alloc((size_t)nbuck * CAP * 4);
  int2* ofl = (int2*)alloc((size_t)OFLCAP * 8);
  int* rowptr = (int*)alloc((size_t)(N + 1) * 4);
  unsigned short* msgb = (unsigned short*)alloc((size_t)N * 128 * 2);
  unsigned short* wqkvp = (unsigned short*)alloc((size_t)128 * 384 * 2);
  unsigned short* wop   = (unsigned short*)alloc((size_t)128 * 128 * 2);
  unsigned short* w1p   = (unsigned short*)alloc((size_t)128 * 256 * 2);
  unsigned short* w2p   = (unsigned short*)alloc((size_t)256 * 128 * 2);
  unsigned short* bqkvb = (unsigned short*)alloc(384 * 2);
  size_t zoff = off;
  int* bfill   = (int*)alloc((size_t)MAXBUCK * 4);
  int* ofl_cnt = (int*)alloc(4);
  hipMemsetAsync(ws + zoff, 0, off - zoff, stream);

  PP pp;
  for (int i = 0; i < 17; ++i) pp.p[i] = d_in[5 + i];

  const int NB2 = (N + 31) / 32;
  const int bb = (E + 4095) / 4096;

  // fused: param prep || binned edge scatter (isf computed inline per wave)
  k_prep<<<B_CONV + 66 + bb, 256, 0, stream>>>(
      pp, (const unsigned*)x, pc, wqkvp, wop, w1p, w2p, bqkvb,
      ei, et, bfill, tmp, ofl, ofl_cnt, E, nbuck, shift, CAP, bb);

  // fused: LN1+QKV (32-row) || per-bucket CSR sort
  k_lnqkv<<<NB2 + nbuck, 256, 0, stream>>>(
      x, pc, bqkvb, wqkvp, qb, kvb, N, NB2,
      tmp, bfill, ofl, ofl_cnt, rowptr, packed, nbuck, shift, CAP);

  // attention (high-occupancy, 512B LDS) -> msgb
  k_attn<<<(N + 3) / 4, 256, 0, stream>>>(qb, kvb, packed, rowptr, pc, msgb, N, th);

  // fused tail: 32-row blocks
  k_tail<<<(N + 31) / 32, 256, 0, stream>>>(x, msgb, wop, w1p, w2p, pc, d_out, N);
}